// Round 9
// baseline (292.777 us; speedup 1.0000x reference)
//
#include <hip/hip_runtime.h>
#include <hip/hip_bf16.h>
#include <math.h>

#define B_ 2
#define S_ 2048
#define E_ 1024
#define H_ 16
#define D_ 64
#define M_ 4096   // B_*S_
#define NT2 32    // D_/2
#define KVB 64

typedef __bf16 bf16;
typedef __bf16 bf16x4 __attribute__((ext_vector_type(4)));
typedef __bf16 bf16x8 __attribute__((ext_vector_type(8)));
typedef float f32x4 __attribute__((ext_vector_type(4)));
typedef float f32x16 __attribute__((ext_vector_type(16)));

__device__ __forceinline__ void gload_lds16(const void* g, void* lds) {
  __builtin_amdgcn_global_load_lds(
      (const __attribute__((address_space(1))) unsigned int*)g,
      (__attribute__((address_space(3))) unsigned int*)lds, 16, 0, 0);
}

#define MFMA16(a, b, c) __builtin_amdgcn_mfma_f32_16x16x32_bf16(a, b, c, 0, 0, 0)
#define MFMA32(a, b, c) __builtin_amdgcn_mfma_f32_32x32x16_bf16(a, b, c, 0, 0, 0)

// ---------------- split fp32 -> bf16 hi/lo ----------------
__global__ __launch_bounds__(256)
void split_f32_kernel(const float* __restrict__ in, bf16* __restrict__ hi,
                      bf16* __restrict__ lo, int n4) {
  int i = blockIdx.x * 256 + threadIdx.x;
  if (i >= n4) return;
  float4 v = ((const float4*)in)[i];
  bf16 h0 = (bf16)v.x, h1 = (bf16)v.y, h2 = (bf16)v.z, h3 = (bf16)v.w;
  bf16x4 hv = {h0, h1, h2, h3};
  bf16x4 lv = {(bf16)(v.x - (float)h0), (bf16)(v.y - (float)h1),
               (bf16)(v.z - (float)h2), (bf16)(v.w - (float)h3)};
  *(bf16x4*)(hi + 4 * (size_t)i) = hv;
  *(bf16x4*)(lo + 4 * (size_t)i) = lv;
}

// ------------- transpose + split, all 4 weights in one launch -------------
__global__ __launch_bounds__(256)
void transpose_split4_kernel(const float* __restrict__ Wq, const float* __restrict__ Wk,
                             const float* __restrict__ Wv, const float* __restrict__ Wo,
                             bf16* __restrict__ Tqh, bf16* __restrict__ Tql,
                             bf16* __restrict__ Tkh, bf16* __restrict__ Tkl,
                             bf16* __restrict__ Tvh, bf16* __restrict__ Tvl,
                             bf16* __restrict__ Toh, bf16* __restrict__ Tol) {
  const int z = blockIdx.z;
  const float* W = z == 0 ? Wq : z == 1 ? Wk : z == 2 ? Wv : Wo;
  bf16* Th = z == 0 ? Tqh : z == 1 ? Tkh : z == 2 ? Tvh : Toh;
  bf16* Tl = z == 0 ? Tql : z == 1 ? Tkl : z == 2 ? Tvl : Tol;
  __shared__ float tile[32][33];
  const int tx = threadIdx.x & 31, ty = threadIdx.x >> 5;  // ty 0..7
  const int c0 = blockIdx.x * 32, r0 = blockIdx.y * 32;
#pragma unroll
  for (int i = 0; i < 4; ++i)
    tile[ty + 8 * i][tx] = W[(size_t)(r0 + ty + 8 * i) * E_ + c0 + tx];
  __syncthreads();
#pragma unroll
  for (int i = 0; i < 4; ++i) {
    int rr = ty + 8 * i;
    float v = tile[tx][rr];  // = W[r0+tx][c0+rr]
    bf16 hv = (bf16)v;
    size_t oidx = (size_t)(c0 + rr) * E_ + r0 + tx;
    Th[oidx] = hv;
    Tl[oidx] = (bf16)(v - (float)hv);
  }
}

// ---------------- RoPE cos/sin table ----------------
__global__ __launch_bounds__(256)
void rope_tab_kernel(const int* __restrict__ pos, float* __restrict__ cosT,
                     float* __restrict__ sinT) {
  int idx = blockIdx.x * 256 + threadIdx.x;  // B_*S_*NT2
  int t = idx & 31, bs = idx >> 5;
  double th = pow(10000.0, -(double)(2 * t) / 64.0);
  float ang = (float)pos[bs] * (float)th;  // fp32 product (matches ref rounding)
  double a = (double)ang;
  cosT[idx] = (float)cos(a);
  sinT[idx] = (float)sin(a);
}

// ------------- fused QKV GEMM: K-concat split-bf16, 256x256, BK=64 ---------
// Split sum AhBh + AhBl + AlBh == ONE bf16 GEMM with K=3072:
//   A' = [Ah | Ah | Al], B' = [Bh ; Bl ; Bh] — segment picked in the stage's
//   address computation (no materialization).
// Template-faithful schedule (m198/m201): 8 waves (2Mx4N), wave tile 128x64
// of 16x16x32 frags (0.375 LDS-reads/MFMA), 4 phases/K-tile: each phase
// {2 prefetch gload_lds | 4 ds_read_b128 (p0: +8 B-frags, held in regs) |
//  s_barrier | setprio(1) 16 MFMA setprio(0) | s_barrier}; vmcnt(0) only at
// the tile boundary (prefetch spans all 4 phases).  Swizzle byte^=(row&7)<<4
// both-sides (pre-swizzled global source, linear LDS dest, XOR on read).
#define BMc 256
#define BNc 256
#define BKc 64
#define KCAT 3072
#define NKC 48  // KCAT/BKc

__global__ __launch_bounds__(512, 1)
void gemm_qkv_kernel(const bf16* __restrict__ Ah_g, const bf16* __restrict__ Al_g,
                     const bf16* __restrict__ BhQ, const bf16* __restrict__ BlQ,
                     const bf16* __restrict__ BhK, const bf16* __restrict__ BlK,
                     const bf16* __restrict__ BhV, const bf16* __restrict__ BlV,
                     const float* __restrict__ bqp, const float* __restrict__ bkp,
                     const float* __restrict__ bvp,
                     const float* __restrict__ cosT, const float* __restrict__ sinT,
                     bf16* __restrict__ Qh, bf16* __restrict__ Qlo,
                     bf16* __restrict__ Kh, bf16* __restrict__ Klo,
                     bf16* __restrict__ VTb) {
  __shared__ bf16 lA[2][BMc * BKc];  // 32 KB each buf
  __shared__ bf16 lB[2][BNc * BKc];  // total 128 KB
  const int tid = threadIdx.x;                // 0..511
  const int lin = blockIdx.x;                 // 0..191
  const int cc = (lin & 7) * 24 + (lin >> 3); // XCD chunk (192 = 8*24)
  const int third = cc >> 6;                  // 0=Q 1=K 2=V
  const int rem = cc & 63;
  const int n0 = (rem >> 4) * BNc;            // consecutive cc share n-panel
  const int m0 = (rem & 15) * BMc;
  const bf16* BhX = third == 0 ? BhQ : third == 1 ? BhK : BhV;
  const bf16* BlX = third == 0 ? BlQ : third == 1 ? BlK : BlV;
  const float* bias = third == 0 ? bqp : third == 1 ? bkp : bvp;
  const int wave = tid >> 6, lane = tid & 63;
  const int wr = wave >> 2, wc = wave & 3;    // 2M x 4N wave grid
  const int c16 = lane & 15, hq = lane >> 4;  // frag col / k-group

  f32x4 acc[8][4] = {};

  // stage one quarter (2 gloads: chunk i of A and of B) of tile kt
  auto stage_q = [&](int kt, int buf, int i) {
    const int seg = kt >> 4;                  // 0,1,2 -> AhBh, AhBl, AlBh
    const int kk0 = (kt & 15) * BKc;
    const bf16* sA = (seg < 2) ? Ah_g : Al_g;
    const bf16* sB = (seg == 1) ? BlX : BhX;
    int c = i * 512 + tid;                    // 16B chunk 0..2047
    int row = c >> 3, u = c & 7;
    int us = u ^ (row & 7);                   // pre-swizzled source slot
    char* lpA = (char*)&lA[buf][0] + (size_t)(i * 512 + wave * 64) * 16;
    char* lpB = (char*)&lB[buf][0] + (size_t)(i * 512 + wave * 64) * 16;
    gload_lds16(sA + (size_t)(m0 + row) * 1024 + kk0 + us * 8, lpA);
    gload_lds16(sB + (size_t)(n0 + row) * 1024 + kk0 + us * 8, lpB);
  };

  // prologue
#pragma unroll
  for (int i = 0; i < 4; ++i) stage_q(0, 0, i);
  asm volatile("s_waitcnt vmcnt(0)" ::: "memory");
  __builtin_amdgcn_s_barrier();

  int cur = 0;
  for (int kt = 0; kt < NKC; ++kt) {
    const bool pf = (kt + 1 < NKC);
    bf16x8 bfr[4][2];  // B-frags, read at phase 0, live across phases
#pragma unroll
    for (int p = 0; p < 4; ++p) {
      if (pf) stage_q(kt + 1, cur ^ 1, p);  // 2 prefetch loads this phase
      if (p == 0) {
#pragma unroll
        for (int ni = 0; ni < 4; ++ni)
#pragma unroll
          for (int ks = 0; ks < 2; ++ks) {
            int brow = wc * 64 + ni * 16 + c16;
            int boff = brow * 128 + ((ks * 64 + hq * 16) ^ ((brow & 7) << 4));
            bfr[ni][ks] = *(const bf16x8*)((const char*)&lB[cur][0] + boff);
          }
      }
      bf16x8 af[2][2];  // A-frags for this phase's two mi rows
#pragma unroll
      for (int s = 0; s < 2; ++s)
#pragma unroll
        for (int ks = 0; ks < 2; ++ks) {
          int arow = wr * 128 + (2 * p + s) * 16 + c16;
          int aoff = arow * 128 + ((ks * 64 + hq * 16) ^ ((arow & 7) << 4));
          af[s][ks] = *(const bf16x8*)((const char*)&lA[cur][0] + aoff);
        }
      __builtin_amdgcn_s_barrier();
      __builtin_amdgcn_s_setprio(1);
#pragma unroll
      for (int s = 0; s < 2; ++s)
#pragma unroll
        for (int ks = 0; ks < 2; ++ks)
#pragma unroll
          for (int ni = 0; ni < 4; ++ni)
            acc[2 * p + s][ni] = MFMA16(af[s][ks], bfr[ni][ks], acc[2 * p + s][ni]);
      __builtin_amdgcn_s_setprio(0);
      __builtin_amdgcn_s_barrier();
    }
    asm volatile("s_waitcnt vmcnt(0)" ::: "memory");  // next tile landed
    __builtin_amdgcn_s_barrier();
    cur ^= 1;
  }

  // ---- epilogue (16x16 C-layout: col=lane&15, row=hq*4+reg) ----
#pragma unroll
  for (int mi = 0; mi < 8; ++mi)
#pragma unroll
    for (int ni = 0; ni < 4; ++ni) {
      const int gcol = n0 + wc * 64 + ni * 16 + c16;
      const float bv = bias[gcol];
      if (third < 2) {  // Q or K: RoPE (+scale for Q), split
        bf16* outH = third == 0 ? Qh : Kh;
        bf16* outL = third == 0 ? Qlo : Klo;
        const int h = gcol >> 6, d = gcol & 63, tt = d >> 1;
#pragma unroll
        for (int reg = 0; reg < 4; ++reg) {
          int grow = m0 + wr * 128 + mi * 16 + hq * 4 + reg;
          int s = grow & (S_ - 1), b = grow >> 11;
          float v = acc[mi][ni][reg] + bv;
          float other = __shfl_xor(v, 1);  // partner dim (d^1), lane^1
          float cs = cosT[(size_t)(b * S_ + s) * NT2 + tt];
          float sn = sinT[(size_t)(b * S_ + s) * NT2 + tt];
          float vr = (d & 1) ? (other * sn + v * cs) : (v * cs - other * sn);
          if (third == 0) vr *= 0.125f;  // 1/sqrt(D)
          bf16 hv = (bf16)vr;
          bf16 lv = (bf16)(vr - (float)hv);
          size_t idx = (((size_t)(b * H_ + h)) * S_ + s) * D_ + d;
          outH[idx] = hv;
          outL[idx] = lv;
        }
      } else {  // V: bf16, transposed [B,H,D,S]; 4 consecutive s per lane
        const int h = gcol >> 6, d = gcol & 63;
        int grow = m0 + wr * 128 + mi * 16 + hq * 4;
        int s = grow & (S_ - 1), b = grow >> 11;
        ushort4 pk;
        unsigned short* pp = (unsigned short*)&pk;
#pragma unroll
        for (int reg = 0; reg < 4; ++reg) {
          float v = acc[mi][ni][reg] + bv;
          bf16 hv = (bf16)v;
          pp[reg] = __builtin_bit_cast(unsigned short, hv);
        }
        *(ushort4*)((unsigned short*)VTb +
                    (((size_t)(b * H_ + h)) * D_ + d) * S_ + s) = pk;
      }
    }
}

// ---------------- O-projection split-bf16 GEMM (128^2, phase-interleaved) ---
#define BMg 128
#define BNg 128
#define BKg 32

__global__ __launch_bounds__(256)
void gemm_o_kernel(const bf16* __restrict__ Ah_g, const bf16* __restrict__ Al_g,
                   const bf16* __restrict__ Bh_g, const bf16* __restrict__ Bl_g,
                   const float* __restrict__ bias, float* __restrict__ outF) {
  __shared__ bf16 lA_h[2][BMg * BKg], lA_l[2][BMg * BKg];
  __shared__ bf16 lB_h[2][BNg * BKg], lB_l[2][BNg * BKg];
  const int tid = threadIdx.x;
  const int lin = blockIdx.x;                 // 0..255
  const int cc = (lin & 7) * 32 + (lin >> 3); // XCD-chunk (256 = 8*32)
  const int nb = cc >> 5;                     // 0..7
  const int mb = cc & 31;
  const int m0 = mb * BMg, n0 = nb * BNg;
  const int wave = tid >> 6, lane = tid & 63;
  const int wr = wave >> 1, wc = wave & 1;
  const int r = lane & 31, half = lane >> 5;
  const int KD = 1024;
  const int NK = KD / BKg;

  f32x16 acc[2][2] = {};

  auto stage_pair = [&](int kt, int buf, int p) {
    const int k0 = kt * BKg;
#pragma unroll
    for (int j = 0; j < 2; ++j) {
      int mm = p * 2 + j;
      const bf16* gs = mm == 0 ? Ah_g : mm == 1 ? Al_g : mm == 2 ? Bh_g : Bl_g;
      bf16* ld = mm == 0 ? &lA_h[buf][0] : mm == 1 ? &lA_l[buf][0]
               : mm == 2 ? &lB_h[buf][0] : &lB_l[buf][0];
      const int rbase = mm < 2 ? m0 : n0;
#pragma unroll
      for (int i = 0; i < 2; ++i) {
        int c = i * 256 + tid;
        int row = c >> 2, u = c & 3;
        int us = u ^ ((row >> 1) & 3);
        const char* gp =
            (const char*)(gs + (size_t)(rbase + row) * KD + k0) + us * 16;
        char* lp = (char*)ld + (size_t)(i * 256 + wave * 64) * 16;
        gload_lds16(gp, lp);
      }
    }
  };

#pragma unroll
  for (int p = 0; p < 2; ++p) stage_pair(0, 0, p);
  asm volatile("s_waitcnt vmcnt(0)" ::: "memory");
  __builtin_amdgcn_s_barrier();

  int cur = 0;
  for (int kt = 0; kt < NK; ++kt) {
    const bool pf = (kt + 1 < NK);
    bf16x8 b_h[2][2], b_l[2][2];  // [ni][ks]
#pragma unroll
    for (int p = 0; p < 2; ++p) {
      if (pf) stage_pair(kt + 1, cur ^ 1, p);
      if (p == 0) {
#pragma unroll
        for (int ni = 0; ni < 2; ++ni)
#pragma unroll
          for (int ks = 0; ks < 2; ++ks) {
            int brow = wc * 64 + ni * 32 + r;
            int boff =
                brow * 64 + ((ks * 32 + half * 16) ^ (((brow >> 1) & 3) << 4));
            b_h[ni][ks] = *(const bf16x8*)((const char*)&lB_h[cur][0] + boff);
            b_l[ni][ks] = *(const bf16x8*)((const char*)&lB_l[cur][0] + boff);
          }
      }
      bf16x8 a_h2[2], a_l2[2];
      const int arow = wr * 64 + p * 32 + r;
#pragma unroll
      for (int ks = 0; ks < 2; ++ks) {
        int aoff =
            arow * 64 + ((ks * 32 + half * 16) ^ (((arow >> 1) & 3) << 4));
        a_h2[ks] = *(const bf16x8*)((const char*)&lA_h[cur][0] + aoff);
        a_l2[ks] = *(const bf16x8*)((const char*)&lA_l[cur][0] + aoff);
      }
      __builtin_amdgcn_s_setprio(1);
#pragma unroll
      for (int ks = 0; ks < 2; ++ks)
#pragma unroll
        for (int ni = 0; ni < 2; ++ni) {
          acc[p][ni] = MFMA32(a_h2[ks], b_h[ni][ks], acc[p][ni]);
          acc[p][ni] = MFMA32(a_h2[ks], b_l[ni][ks], acc[p][ni]);
          acc[p][ni] = MFMA32(a_l2[ks], b_h[ni][ks], acc[p][ni]);
        }
      __builtin_amdgcn_s_setprio(0);
    }
    if (pf) asm volatile("s_waitcnt vmcnt(0)" ::: "memory");
    __builtin_amdgcn_s_barrier();
    cur ^= 1;
  }

#pragma unroll
  for (int mi = 0; mi < 2; ++mi)
#pragma unroll
    for (int ni = 0; ni < 2; ++ni) {
      const int gcol = n0 + wc * 64 + ni * 32 + r;
      const float bv = bias[gcol];
#pragma unroll
      for (int tq = 0; tq < 4; ++tq)
#pragma unroll
        for (int u = 0; u < 4; ++u) {
          int grow = m0 + wr * 64 + mi * 32 + (u + 8 * tq + 4 * half);
          outF[(size_t)grow * E_ + gcol] = acc[mi][ni][tq * 4 + u] + bv;
        }
    }
}

// ---------------- flash attention (in-register softmax, swapped QK^T) -------
__global__ __launch_bounds__(256)
void attn_kernel(const bf16* __restrict__ Qh, const bf16* __restrict__ Ql,
                 const bf16* __restrict__ Kh, const bf16* __restrict__ Kl,
                 const bf16* __restrict__ VT, bf16* __restrict__ Ch,
                 bf16* __restrict__ Cl) {
  __shared__ bf16 sKh[2][KVB * 64];
  __shared__ bf16 sKl[2][KVB * 64];
  __shared__ bf16 sV[2][KVB * 64];  // [d=64][key-pos=64], row-XOR-swizzled

  const int tid = threadIdx.x;
  const int wave = tid >> 6, lane = tid & 63;
  const int r = lane & 15, hq = lane >> 4;
  const int bid = blockIdx.x;
  const int swz = (bid & 7) * 64 + (bid >> 3);  // XCD-chunked (512 % 8 == 0)
  const int bh = swz >> 4, qblk = swz & 15;
  const int q0 = qblk * 128 + wave * 32;
  const size_t hb = (size_t)bh * (S_ * D_);
  const size_t vb = (size_t)bh * (D_ * S_);

  // Q fragments in registers (B-operand of swapped QK^T; layout unchanged)
  bf16x8 qh[2][2], ql[2][2];
#pragma unroll
  for (int mi = 0; mi < 2; ++mi)
#pragma unroll
    for (int ks = 0; ks < 2; ++ks) {
      size_t off = hb + (size_t)(q0 + mi * 16 + r) * D_ + ks * 32 + hq * 8;
      qh[mi][ks] = *(const bf16x8*)&Qh[off];
      ql[mi][ks] = *(const bf16x8*)&Ql[off];
    }

  float m_lane[2] = {-1e30f, -1e30f};  // running max for q = r, per mi
  float l_lane[2] = {0.f, 0.f};        // per-lane partial denominator
  f32x4 o[2][4] = {};

  // K staging: global_load_lds, XOR-swizzled via pre-swizzled source chunks
  auto stageK = [&](int kt, int buf) {
    const bf16* kbh = Kh + hb + (size_t)kt * (KVB * D_);
    const bf16* kbl = Kl + hb + (size_t)kt * (KVB * D_);
#pragma unroll
    for (int i = 0; i < 2; ++i) {
      int c = i * 256 + tid;
      int ldo = (i * 256 + wave * 64) * 16;
      int cs = c ^ ((c >> 3) & 7);
      gload_lds16(kbh + cs * 8, (char*)&sKh[buf][0] + ldo);
      gload_lds16(kbl + cs * 8, (char*)&sKl[buf][0] + ldo);
    }
  };
  // V staging part 1: issue global loads into registers
  uint4 vld[2];
  auto loadV = [&](int kt) {
    const bf16* vbp = VT + vb + kt * KVB;
#pragma unroll
    for (int i = 0; i < 2; ++i) {
      int c = i * 256 + tid;
      int row = c >> 3, w = c & 7;  // row = d, w = key-chunk
      vld[i] = *(const uint4*)(vbp + (size_t)row * S_ + w * 8);
    }
  };
  // V staging part 2: ds_write in permuted-column order + row-XOR swizzle
  auto writeV = [&](int buf) {
#pragma unroll
    for (int i = 0; i < 2; ++i) {
      int c = i * 256 + tid;
      int row = c >> 3, w = c & 7;
      int pb0 = (w >> 2) * 32 + (w & 1) * 16 + ((w >> 1) & 1) * 4;  // elems
      char* base = (char*)&sV[buf][0] + row * 128;
      uint2 lo = {vld[i].x, vld[i].y};  // keys w*8+0..3 -> pos pb0..pb0+3
      uint2 hi = {vld[i].z, vld[i].w};  // keys w*8+4..7 -> pos pb0+8..pb0+11
      *(uint2*)(base + ((pb0 * 2) ^ ((row & 7) << 4))) = lo;
      *(uint2*)(base + (((pb0 + 8) * 2) ^ ((row & 7) << 4))) = hi;
    }
  };

  stageK(0, 0);
  loadV(0);
  writeV(0);
  __syncthreads();
  int cur = 0;

  for (int kt = 0; kt < S_ / KVB; ++kt) {
    if (kt + 1 < S_ / KVB) {
      stageK(kt + 1, cur ^ 1);
      loadV(kt + 1);  // issue early; write after PV (latency hidden)
    }

    // ---- QK^T (swapped: A=K, B=Q) -> sf[mi][nf][j]: key nf*16+hq*4+j, q=r
    f32x4 sf[2][4] = {};
#pragma unroll
    for (int nf = 0; nf < 4; ++nf)
#pragma unroll
      for (int ks = 0; ks < 2; ++ks) {
        int kk = nf * 16 + r;
        int boff = (kk * 128 + ks * 64 + hq * 16) ^ ((kk & 7) << 4);
        bf16x8 kkh = *(const bf16x8*)((const char*)&sKh[cur][0] + boff);
        bf16x8 kkl = *(const bf16x8*)((const char*)&sKl[cur][0] + boff);
#pragma unroll
        for (int mi = 0; mi < 2; ++mi) {
          sf[mi][nf] = MFMA16(kkh, qh[mi][ks], sf[mi][nf]);
          sf[mi][nf] = MFMA16(kkh, ql[mi][ks], sf[mi][nf]);
          sf[mi][nf] = MFMA16(kkl, qh[mi][ks], sf[mi][nf]);
        }
      }

    // ---- defer-max online softmax (lane-local fast path) ----
    float lmax[2];
#pragma unroll
    for (int mi = 0; mi < 2; ++mi) {
      f32x4 m4;
#pragma unroll
      for (int e = 0; e < 4; ++e)
        m4[e] = fmaxf(fmaxf(sf[mi][0][e], sf[mi][1][e]),
                      fmaxf(sf[mi][2][e], sf[mi][3][e]));
      lmax[mi] = fmaxf(fmaxf(m4[0], m4[1]), fmaxf(m4[2], m4[3]));
    }
    int need = (lmax[0] > m_lane[0] + 8.f) || (lmax[1] > m_lane[1] + 8.f);
    if (__any(need)) {  // slow path: recompute full max, rescale o & l
#pragma unroll
      for (int mi = 0; mi < 2; ++mi) {
        float mx = lmax[mi];
        mx = fmaxf(mx, __shfl_xor(mx, 16));
        mx = fmaxf(mx, __shfl_xor(mx, 32));
        float mn = fmaxf(m_lane[mi], mx);
        float al = __expf(m_lane[mi] - mn);
        l_lane[mi] *= al;
        m_lane[mi] = mn;
        int alb = __builtin_bit_cast(int, al);
#pragma unroll
        for (int j = 0; j < 4; ++j) {
          int g = __builtin_amdgcn_ds_bpermute((hq * 4 + j) * 4, alb);
          float a = __builtin_bit_cast(float, g);
#pragma unroll
          for (int nd = 0; nd < 4; ++nd) o[mi][nd][j] *= a;
        }
      }
    }
    // exp + per-lane partial l + pa fragments (P in registers)
    bf16x8 pa[2][2];
#pragma unroll
    for (int mi = 0; mi < 2; ++mi) {
      f32x4 s4 = {};
#pragma unroll
      for (int nf = 0; nf < 4; ++nf)
#pragma unroll
        for (int e = 0; e < 4; ++e) {
          float pv = __expf(sf[mi][nf][e] - m_lane[mi]);
          sf[mi][nf][e] = pv;
          s4[e] += pv;
        }
      l_lane[mi] += s4[0] + s4[1] + s4[2] + s4[3];
#pragma unroll
      for (int ks = 0; ks < 2; ++ks) {
        bf16x8 t;
#pragma unroll
        for (int e = 0; e < 4; ++e) {
          t[e] = (bf16)sf[mi][2 * ks][e];
          t[4 + e] = (bf16)sf[mi][2 * ks + 1][e];
        }
        pa[mi][ks] = t;
      }
    }

    // ---- PV: B-frags from sV (permuted cols match pa key order) ----
#pragma unroll
    for (int nd = 0; nd < 4; ++nd)
#pragma unroll
      for (int ks = 0; ks < 2; ++ks) {
        int dd = nd * 16 + r;
        int boff = (dd * 128 + ks * 64 + hq * 16) ^ ((dd & 7) << 4);
        bf16x8 vv = *(const bf16x8*)((const char*)&sV[cur][0] + boff);
#pragma unroll
        for (int mi = 0; mi < 2; ++mi)
          o[mi][nd] = MFMA16(pa[mi][ks], vv, o[mi][nd]);
      }

    if (kt + 1 < S_ / KVB) writeV(cur ^ 1);  // sV[cur^1] unread this iter
    __syncthreads();  // drains vmcnt(0)/lgkmcnt(0): next tile ready
    cur ^= 1;
  }

  // ---- epilogue: reduce l, broadcast to o-lanes, normalize, split, store ---
  const int b = bh >> 4, h = bh & 15;
  float lq[2][4];
#pragma unroll
  for (int mi = 0; mi < 2; ++mi) {
    float lr = l_lane[mi];
    lr += __shfl_xor(lr, 16);
    lr += __shfl_xor(lr, 32);
    int lb = __builtin_bit_cast(int, lr);
#pragma unroll
    for (int j = 0; j < 4; ++j) {
      int g = __builtin_amdgcn_ds_bpermute((hq * 4 + j) * 4, lb);
      lq[mi][j] = __builtin_bit_cast(float, g);
    }
  }
#pragma unroll
  for (int mi = 0; mi < 2; ++mi)
#pragma unroll
    for (int nd = 0; nd < 4; ++nd)
#pragma unroll
      for (int j = 0; j < 4; ++j) {
        int s = q0 + mi * 16 + hq * 4 + j;
        int d = nd * 16 + r;
        float ov = o[mi][nd][j] / lq[mi][j];
        bf16 hv = (bf16)ov;
        bf16 lv = (bf16)(ov - (float)hv);
        size_t idx = (((size_t)(b * S_ + s)) * H_ + h) * D_ + d;
        Ch[idx] = hv;
        Cl[idx] = lv;
      }
}

// ---------------- host ----------------
extern "C" void kernel_launch(void* const* d_in, const int* in_sizes, int n_in,
                              void* d_out, int out_size, void* d_ws, size_t ws_size,
                              hipStream_t stream) {
  const float* x = (const float*)d_in[0];
  const int* pos = (const int*)d_in[1];
  const float* Wq = (const float*)d_in[2];
  const float* bq = (const float*)d_in[3];
  const float* Wk = (const float*)d_in[4];
  const float* bk = (const float*)d_in[5];
  const float* Wv = (const float*)d_in[6];
  const float* bv = (const float*)d_in[7];
  const float* Wo = (const float*)d_in[8];
  const float* bo = (const float*)d_in[9];
  float* out = (float*)d_out;

  char* p = (char*)d_ws;
  auto alloc = [&](size_t bytes) {
    char* rp = p;
    p += (bytes + 255) & ~(size_t)255;
    return rp;
  };
  const size_t XB = (size_t)M_ * E_ * sizeof(bf16);        // 8 MiB
  const size_t WB = (size_t)E_ * E_ * sizeof(bf16);        // 2 MiB
  const size_t TB = (size_t)B_ * S_ * NT2 * sizeof(float); // 256 KiB
  bf16* Xh = (bf16*)alloc(XB);
  bf16* Xl = (bf16*)alloc(XB);
  bf16* WqTh = (bf16*)alloc(WB); bf16* WqTl = (bf16*)alloc(WB);
  bf16* WkTh = (bf16*)alloc(WB); bf16* WkTl = (bf16*)alloc(WB);
  bf16* WvTh = (bf16*)alloc(WB); bf16* WvTl = (bf16*)alloc(WB);
  bf16* WoTh = (bf16*)alloc(WB); bf16* WoTl = (bf16*)alloc(WB);
  float* cosT = (float*)alloc(TB);
  float* sinT = (float*)alloc(TB);
  bf16* Qh = (bf16*)alloc(XB); bf16* Qlo = (bf16*)alloc(XB);
  bf16* Kh = (bf16*)alloc(XB); bf16* Klo = (bf16*)alloc(XB);
  bf16* VTb = (bf16*)alloc(XB);
  // ctx aliases X (X is dead after the QKV GEMM; attn runs after on same stream)
  bf16* Ch = Xh;
  bf16* Cl = Xl;

  split_f32_kernel<<<M_ * E_ / 4 / 256, 256, 0, stream>>>(x, Xh, Xl, M_ * E_ / 4);
  dim3 tg(32, 32, 4);
  transpose_split4_kernel<<<tg, 256, 0, stream>>>(Wq, Wk, Wv, Wo, WqTh, WqTl,
                                                  WkTh, WkTl, WvTh, WvTl, WoTh,
                                                  WoTl);
  rope_tab_kernel<<<B_ * S_ * NT2 / 256, 256, 0, stream>>>(pos, cosT, sinT);

  gemm_qkv_kernel<<<192, 512, 0, stream>>>(Xh, Xl, WqTh, WqTl, WkTh, WkTl, WvTh,
                                           WvTl, bq, bk, bv, cosT, sinT, Qh, Qlo,
                                           Kh, Klo, VTb);

  attn_kernel<<<B_ * H_ * (S_ / 128), 256, 0, stream>>>(Qh, Qlo, Kh, Klo, VTb,
                                                        Ch, Cl);

  gemm_o_kernel<<<256, 256, 0, stream>>>(Ch, Cl, WoTh, WoTl, bo, out);
}

// Round 10
// 240.435 us; speedup vs baseline: 1.2177x; 1.2177x over previous
//
#include <hip/hip_runtime.h>
#include <hip/hip_bf16.h>
#include <math.h>

#define B_ 2
#define S_ 2048
#define E_ 1024
#define H_ 16
#define D_ 64
#define M_ 4096   // B_*S_
#define NT2 32    // D_/2
#define KVB 64

typedef __bf16 bf16;
typedef __bf16 bf16x4 __attribute__((ext_vector_type(4)));
typedef __bf16 bf16x8 __attribute__((ext_vector_type(8)));
typedef float f32x4 __attribute__((ext_vector_type(4)));
typedef float f32x16 __attribute__((ext_vector_type(16)));

__device__ __forceinline__ void gload_lds16(const void* g, void* lds) {
  __builtin_amdgcn_global_load_lds(
      (const __attribute__((address_space(1))) unsigned int*)g,
      (__attribute__((address_space(3))) unsigned int*)lds, 16, 0, 0);
}

#define MFMA16(a, b, c) __builtin_amdgcn_mfma_f32_16x16x32_bf16(a, b, c, 0, 0, 0)
#define MFMA32(a, b, c) __builtin_amdgcn_mfma_f32_32x32x16_bf16(a, b, c, 0, 0, 0)

// ---------------- split fp32 -> bf16 hi/lo ----------------
__global__ __launch_bounds__(256)
void split_f32_kernel(const float* __restrict__ in, bf16* __restrict__ hi,
                      bf16* __restrict__ lo, int n4) {
  int i = blockIdx.x * 256 + threadIdx.x;
  if (i >= n4) return;
  float4 v = ((const float4*)in)[i];
  bf16 h0 = (bf16)v.x, h1 = (bf16)v.y, h2 = (bf16)v.z, h3 = (bf16)v.w;
  bf16x4 hv = {h0, h1, h2, h3};
  bf16x4 lv = {(bf16)(v.x - (float)h0), (bf16)(v.y - (float)h1),
               (bf16)(v.z - (float)h2), (bf16)(v.w - (float)h3)};
  *(bf16x4*)(hi + 4 * (size_t)i) = hv;
  *(bf16x4*)(lo + 4 * (size_t)i) = lv;
}

// ------------- transpose + split, all 4 weights in one launch -------------
__global__ __launch_bounds__(256)
void transpose_split4_kernel(const float* __restrict__ Wq, const float* __restrict__ Wk,
                             const float* __restrict__ Wv, const float* __restrict__ Wo,
                             bf16* __restrict__ Tqh, bf16* __restrict__ Tql,
                             bf16* __restrict__ Tkh, bf16* __restrict__ Tkl,
                             bf16* __restrict__ Tvh, bf16* __restrict__ Tvl,
                             bf16* __restrict__ Toh, bf16* __restrict__ Tol) {
  const int z = blockIdx.z;
  const float* W = z == 0 ? Wq : z == 1 ? Wk : z == 2 ? Wv : Wo;
  bf16* Th = z == 0 ? Tqh : z == 1 ? Tkh : z == 2 ? Tvh : Toh;
  bf16* Tl = z == 0 ? Tql : z == 1 ? Tkl : z == 2 ? Tvl : Tol;
  __shared__ float tile[32][33];
  const int tx = threadIdx.x & 31, ty = threadIdx.x >> 5;  // ty 0..7
  const int c0 = blockIdx.x * 32, r0 = blockIdx.y * 32;
#pragma unroll
  for (int i = 0; i < 4; ++i)
    tile[ty + 8 * i][tx] = W[(size_t)(r0 + ty + 8 * i) * E_ + c0 + tx];
  __syncthreads();
#pragma unroll
  for (int i = 0; i < 4; ++i) {
    int rr = ty + 8 * i;
    float v = tile[tx][rr];  // = W[r0+tx][c0+rr]
    bf16 hv = (bf16)v;
    size_t oidx = (size_t)(c0 + rr) * E_ + r0 + tx;
    Th[oidx] = hv;
    Tl[oidx] = (bf16)(v - (float)hv);
  }
}

// ---------------- RoPE cos/sin table ----------------
__global__ __launch_bounds__(256)
void rope_tab_kernel(const int* __restrict__ pos, float* __restrict__ cosT,
                     float* __restrict__ sinT) {
  int idx = blockIdx.x * 256 + threadIdx.x;  // B_*S_*NT2
  int t = idx & 31, bs = idx >> 5;
  double th = pow(10000.0, -(double)(2 * t) / 64.0);
  float ang = (float)pos[bs] * (float)th;  // fp32 product (matches ref rounding)
  double a = (double)ang;
  cosT[idx] = (float)cos(a);
  sinT[idx] = (float)sin(a);
}

// ---------------- fused QKV split-bf16 GEMM, 128^2, 8 waves ----------------
// r4's proven structure (single-buffer, BK=32, slot-swizzle u^=(row>>1)&3 via
// pre-swizzled global source, 2x __syncthreads) with 512 threads = 8 waves
// (2M x 4N, wave tile 64x32): LDS stays 32KB -> 2 blocks/CU = 16 waves/CU
// (vs 12) with finer 12-MFMA bursts per wave -> more latency-hiding
// interleave on each SIMD (Guideline 1; the one untried axis after r4-r9
// schedule variants all pinned at ~130us).
#define BMg 128
#define BNg 128
#define BKg 32

__global__ __launch_bounds__(512, 4)
void gemm_qkv_kernel(const bf16* __restrict__ Ah_g, const bf16* __restrict__ Al_g,
                     const bf16* __restrict__ BhQ, const bf16* __restrict__ BlQ,
                     const bf16* __restrict__ BhK, const bf16* __restrict__ BlK,
                     const bf16* __restrict__ BhV, const bf16* __restrict__ BlV,
                     const float* __restrict__ bqp, const float* __restrict__ bkp,
                     const float* __restrict__ bvp,
                     const float* __restrict__ cosT, const float* __restrict__ sinT,
                     bf16* __restrict__ Qh, bf16* __restrict__ Qlo,
                     bf16* __restrict__ Kh, bf16* __restrict__ Klo,
                     bf16* __restrict__ VTb) {
  __shared__ bf16 lA_h[BMg * BKg], lA_l[BMg * BKg];
  __shared__ bf16 lB_h[BNg * BKg], lB_l[BNg * BKg];
  const int tid = threadIdx.x;        // 0..511
  const int nb = blockIdx.x;          // 0..23
  const int third = nb >> 3;          // 0=Q 1=K 2=V
  const int n0 = (nb & 7) * BNg;
  const int m0 = blockIdx.y * BMg;
  const bf16* Bh_g = third == 0 ? BhQ : third == 1 ? BhK : BhV;
  const bf16* Bl_g = third == 0 ? BlQ : third == 1 ? BlK : BlV;
  const float* bias = third == 0 ? bqp : third == 1 ? bkp : bvp;
  const int wave = tid >> 6, lane = tid & 63;
  const int wr = wave >> 2, wc = wave & 3;  // 2M x 4N wave grid
  const int r = lane & 31, half = lane >> 5;
  const int KD = 1024;

  f32x16 acc[2] = {};  // mi = 0,1 (rows wr*64+mi*32); single 32-col block

  for (int kt = 0; kt < KD / BKg; ++kt) {
    const int k0 = kt * BKg;
    {
      const bf16* gsrc[4] = {Ah_g, Al_g, Bh_g, Bl_g};
      bf16* ldst[4] = {lA_h, lA_l, lB_h, lB_l};
      const int rs[4] = {m0, m0, n0, n0};
#pragma unroll
      for (int mm = 0; mm < 4; ++mm) {
        int c = tid;                    // one 16B chunk per thread per array
        int row = c >> 2, u = c & 3;
        int us = u ^ ((row >> 1) & 3);  // pre-swizzled source slot
        const char* gp =
            (const char*)(gsrc[mm] + (size_t)(rs[mm] + row) * KD + k0) + us * 16;
        char* lp = (char*)ldst[mm] + (size_t)(wave * 64) * 16;
        gload_lds16(gp, lp);
      }
    }
    __syncthreads();
#pragma unroll
    for (int ks = 0; ks < 2; ++ks) {
      bf16x8 a_h[2], a_l[2], b_h, b_l;
#pragma unroll
      for (int mi = 0; mi < 2; ++mi) {
        int row = wr * 64 + mi * 32 + r;
        int boff = row * 64 + ((ks * 32 + half * 16) ^ (((row >> 1) & 3) << 4));
        a_h[mi] = *(const bf16x8*)((const char*)lA_h + boff);
        a_l[mi] = *(const bf16x8*)((const char*)lA_l + boff);
      }
      {
        int row = wc * 32 + r;
        int boff = row * 64 + ((ks * 32 + half * 16) ^ (((row >> 1) & 3) << 4));
        b_h = *(const bf16x8*)((const char*)lB_h + boff);
        b_l = *(const bf16x8*)((const char*)lB_l + boff);
      }
      __builtin_amdgcn_s_setprio(1);
#pragma unroll
      for (int mi = 0; mi < 2; ++mi) {
        acc[mi] = MFMA32(a_h[mi], b_h, acc[mi]);
        acc[mi] = MFMA32(a_h[mi], b_l, acc[mi]);
        acc[mi] = MFMA32(a_l[mi], b_h, acc[mi]);
      }
      __builtin_amdgcn_s_setprio(0);
    }
    __syncthreads();
  }

  // ---- epilogue ----
#pragma unroll
  for (int mi = 0; mi < 2; ++mi) {
    const int gcol = n0 + wc * 32 + r;
    const float bv = bias[gcol];
    if (third < 2) {  // Q or K: RoPE (+scale for Q), split
      bf16* outH = third == 0 ? Qh : Kh;
      bf16* outL = third == 0 ? Qlo : Klo;
      const int h = gcol >> 6, d = gcol & 63, tt = d >> 1;
#pragma unroll
      for (int tq = 0; tq < 4; ++tq) {
#pragma unroll
        for (int u = 0; u < 4; ++u) {
          int reg = tq * 4 + u;
          int grow = m0 + wr * 64 + mi * 32 + (u + 8 * tq + 4 * half);
          int s = grow & (S_ - 1), b = grow >> 11;
          float v = acc[mi][reg] + bv;
          float other = __shfl_xor(v, 1);  // partner dim (d^1), lane^1
          float cs = cosT[(size_t)(b * S_ + s) * NT2 + tt];
          float sn = sinT[(size_t)(b * S_ + s) * NT2 + tt];
          float vr = (d & 1) ? (other * sn + v * cs) : (v * cs - other * sn);
          if (third == 0) vr *= 0.125f;  // 1/sqrt(D)
          bf16 hv = (bf16)vr;
          bf16 lv = (bf16)(vr - (float)hv);
          size_t idx = (((size_t)(b * H_ + h)) * S_ + s) * D_ + d;
          outH[idx] = hv;
          outL[idx] = lv;
        }
      }
    } else {  // V: bf16, transposed [B,H,D,S]
      const int h = gcol >> 6, d = gcol & 63;
#pragma unroll
      for (int tq = 0; tq < 4; ++tq) {
        int grow = m0 + wr * 64 + mi * 32 + (8 * tq + 4 * half);
        int s = grow & (S_ - 1), b = grow >> 11;
        ushort4 pk;
        unsigned short* pp = (unsigned short*)&pk;
#pragma unroll
        for (int u = 0; u < 4; ++u) {
          float v = acc[mi][tq * 4 + u] + bv;
          bf16 hv = (bf16)v;
          pp[u] = __builtin_bit_cast(unsigned short, hv);
        }
        *(ushort4*)((unsigned short*)VTb +
                    (((size_t)(b * H_ + h)) * D_ + d) * S_ + s) = pk;
      }
    }
  }
}

// ---------------- O-projection split-bf16 GEMM (128^2, 8 waves) ------------
__global__ __launch_bounds__(512, 4)
void gemm_o_kernel(const bf16* __restrict__ Ah_g, const bf16* __restrict__ Al_g,
                   const bf16* __restrict__ Bh_g, const bf16* __restrict__ Bl_g,
                   const float* __restrict__ bias, float* __restrict__ outF) {
  __shared__ bf16 lA_h[BMg * BKg], lA_l[BMg * BKg];
  __shared__ bf16 lB_h[BNg * BKg], lB_l[BNg * BKg];
  const int tid = threadIdx.x;
  const int m0 = blockIdx.y * BMg, n0 = blockIdx.x * BNg;
  const int wave = tid >> 6, lane = tid & 63;
  const int wr = wave >> 2, wc = wave & 3;
  const int r = lane & 31, half = lane >> 5;
  const int KD = 1024;

  f32x16 acc[2] = {};

  for (int kt = 0; kt < KD / BKg; ++kt) {
    const int k0 = kt * BKg;
    {
      const bf16* gsrc[4] = {Ah_g, Al_g, Bh_g, Bl_g};
      bf16* ldst[4] = {lA_h, lA_l, lB_h, lB_l};
      const int rs[4] = {m0, m0, n0, n0};
#pragma unroll
      for (int mm = 0; mm < 4; ++mm) {
        int c = tid;
        int row = c >> 2, u = c & 3;
        int us = u ^ ((row >> 1) & 3);
        const char* gp =
            (const char*)(gsrc[mm] + (size_t)(rs[mm] + row) * KD + k0) + us * 16;
        char* lp = (char*)ldst[mm] + (size_t)(wave * 64) * 16;
        gload_lds16(gp, lp);
      }
    }
    __syncthreads();
#pragma unroll
    for (int ks = 0; ks < 2; ++ks) {
      bf16x8 a_h[2], a_l[2], b_h, b_l;
#pragma unroll
      for (int mi = 0; mi < 2; ++mi) {
        int row = wr * 64 + mi * 32 + r;
        int boff = row * 64 + ((ks * 32 + half * 16) ^ (((row >> 1) & 3) << 4));
        a_h[mi] = *(const bf16x8*)((const char*)lA_h + boff);
        a_l[mi] = *(const bf16x8*)((const char*)lA_l + boff);
      }
      {
        int row = wc * 32 + r;
        int boff = row * 64 + ((ks * 32 + half * 16) ^ (((row >> 1) & 3) << 4));
        b_h = *(const bf16x8*)((const char*)lB_h + boff);
        b_l = *(const bf16x8*)((const char*)lB_l + boff);
      }
      __builtin_amdgcn_s_setprio(1);
#pragma unroll
      for (int mi = 0; mi < 2; ++mi) {
        acc[mi] = MFMA32(a_h[mi], b_h, acc[mi]);
        acc[mi] = MFMA32(a_h[mi], b_l, acc[mi]);
        acc[mi] = MFMA32(a_l[mi], b_h, acc[mi]);
      }
      __builtin_amdgcn_s_setprio(0);
    }
    __syncthreads();
  }

#pragma unroll
  for (int mi = 0; mi < 2; ++mi) {
    const int gcol = n0 + wc * 32 + r;
    const float bv = bias[gcol];
#pragma unroll
    for (int tq = 0; tq < 4; ++tq)
#pragma unroll
      for (int u = 0; u < 4; ++u) {
        int grow = m0 + wr * 64 + mi * 32 + (u + 8 * tq + 4 * half);
        outF[(size_t)grow * E_ + gcol] = acc[mi][tq * 4 + u] + bv;
      }
  }
}

// ---------------- flash attention (in-register softmax, swapped QK^T) -------
// + T5 setprio around the two MFMA clusters (m191: +4-7% on attn; blocks are
// independent, waves at different phases -> scheduler has roles to arbitrate).
__global__ __launch_bounds__(256)
void attn_kernel(const bf16* __restrict__ Qh, const bf16* __restrict__ Ql,
                 const bf16* __restrict__ Kh, const bf16* __restrict__ Kl,
                 const bf16* __restrict__ VT, bf16* __restrict__ Ch,
                 bf16* __restrict__ Cl) {
  __shared__ bf16 sKh[2][KVB * 64];
  __shared__ bf16 sKl[2][KVB * 64];
  __shared__ bf16 sV[2][KVB * 64];  // [d=64][key-pos=64], row-XOR-swizzled

  const int tid = threadIdx.x;
  const int wave = tid >> 6, lane = tid & 63;
  const int r = lane & 15, hq = lane >> 4;
  const int bid = blockIdx.x;
  const int swz = (bid & 7) * 64 + (bid >> 3);  // XCD-chunked (512 % 8 == 0)
  const int bh = swz >> 4, qblk = swz & 15;
  const int q0 = qblk * 128 + wave * 32;
  const size_t hb = (size_t)bh * (S_ * D_);
  const size_t vb = (size_t)bh * (D_ * S_);

  bf16x8 qh[2][2], ql[2][2];
#pragma unroll
  for (int mi = 0; mi < 2; ++mi)
#pragma unroll
    for (int ks = 0; ks < 2; ++ks) {
      size_t off = hb + (size_t)(q0 + mi * 16 + r) * D_ + ks * 32 + hq * 8;
      qh[mi][ks] = *(const bf16x8*)&Qh[off];
      ql[mi][ks] = *(const bf16x8*)&Ql[off];
    }

  float m_lane[2] = {-1e30f, -1e30f};
  float l_lane[2] = {0.f, 0.f};
  f32x4 o[2][4] = {};

  auto stageK = [&](int kt, int buf) {
    const bf16* kbh = Kh + hb + (size_t)kt * (KVB * D_);
    const bf16* kbl = Kl + hb + (size_t)kt * (KVB * D_);
#pragma unroll
    for (int i = 0; i < 2; ++i) {
      int c = i * 256 + tid;
      int ldo = (i * 256 + wave * 64) * 16;
      int cs = c ^ ((c >> 3) & 7);
      gload_lds16(kbh + cs * 8, (char*)&sKh[buf][0] + ldo);
      gload_lds16(kbl + cs * 8, (char*)&sKl[buf][0] + ldo);
    }
  };
  uint4 vld[2];
  auto loadV = [&](int kt) {
    const bf16* vbp = VT + vb + kt * KVB;
#pragma unroll
    for (int i = 0; i < 2; ++i) {
      int c = i * 256 + tid;
      int row = c >> 3, w = c & 7;
      vld[i] = *(const uint4*)(vbp + (size_t)row * S_ + w * 8);
    }
  };
  auto writeV = [&](int buf) {
#pragma unroll
    for (int i = 0; i < 2; ++i) {
      int c = i * 256 + tid;
      int row = c >> 3, w = c & 7;
      int pb0 = (w >> 2) * 32 + (w & 1) * 16 + ((w >> 1) & 1) * 4;
      char* base = (char*)&sV[buf][0] + row * 128;
      uint2 lo = {vld[i].x, vld[i].y};
      uint2 hi = {vld[i].z, vld[i].w};
      *(uint2*)(base + ((pb0 * 2) ^ ((row & 7) << 4))) = lo;
      *(uint2*)(base + (((pb0 + 8) * 2) ^ ((row & 7) << 4))) = hi;
    }
  };

  stageK(0, 0);
  loadV(0);
  writeV(0);
  __syncthreads();
  int cur = 0;

  for (int kt = 0; kt < S_ / KVB; ++kt) {
    if (kt + 1 < S_ / KVB) {
      stageK(kt + 1, cur ^ 1);
      loadV(kt + 1);
    }

    // ---- QK^T (swapped: A=K, B=Q) ----
    f32x4 sf[2][4] = {};
    __builtin_amdgcn_s_setprio(1);
#pragma unroll
    for (int nf = 0; nf < 4; ++nf)
#pragma unroll
      for (int ks = 0; ks < 2; ++ks) {
        int kk = nf * 16 + r;
        int boff = (kk * 128 + ks * 64 + hq * 16) ^ ((kk & 7) << 4);
        bf16x8 kkh = *(const bf16x8*)((const char*)&sKh[cur][0] + boff);
        bf16x8 kkl = *(const bf16x8*)((const char*)&sKl[cur][0] + boff);
#pragma unroll
        for (int mi = 0; mi < 2; ++mi) {
          sf[mi][nf] = MFMA16(kkh, qh[mi][ks], sf[mi][nf]);
          sf[mi][nf] = MFMA16(kkh, ql[mi][ks], sf[mi][nf]);
          sf[mi][nf] = MFMA16(kkl, qh[mi][ks], sf[mi][nf]);
        }
      }
    __builtin_amdgcn_s_setprio(0);

    // ---- defer-max online softmax (lane-local fast path) ----
    float lmax[2];
#pragma unroll
    for (int mi = 0; mi < 2; ++mi) {
      f32x4 m4;
#pragma unroll
      for (int e = 0; e < 4; ++e)
        m4[e] = fmaxf(fmaxf(sf[mi][0][e], sf[mi][1][e]),
                      fmaxf(sf[mi][2][e], sf[mi][3][e]));
      lmax[mi] = fmaxf(fmaxf(m4[0], m4[1]), fmaxf(m4[2], m4[3]));
    }
    int need = (lmax[0] > m_lane[0] + 8.f) || (lmax[1] > m_lane[1] + 8.f);
    if (__any(need)) {
#pragma unroll
      for (int mi = 0; mi < 2; ++mi) {
        float mx = lmax[mi];
        mx = fmaxf(mx, __shfl_xor(mx, 16));
        mx = fmaxf(mx, __shfl_xor(mx, 32));
        float mn = fmaxf(m_lane[mi], mx);
        float al = __expf(m_lane[mi] - mn);
        l_lane[mi] *= al;
        m_lane[mi] = mn;
        int alb = __builtin_bit_cast(int, al);
#pragma unroll
        for (int j = 0; j < 4; ++j) {
          int g = __builtin_amdgcn_ds_bpermute((hq * 4 + j) * 4, alb);
          float a = __builtin_bit_cast(float, g);
#pragma unroll
          for (int nd = 0; nd < 4; ++nd) o[mi][nd][j] *= a;
        }
      }
    }
    bf16x8 pa[2][2];
#pragma unroll
    for (int mi = 0; mi < 2; ++mi) {
      f32x4 s4 = {};
#pragma unroll
      for (int nf = 0; nf < 4; ++nf)
#pragma unroll
        for (int e = 0; e < 4; ++e) {
          float pv = __expf(sf[mi][nf][e] - m_lane[mi]);
          sf[mi][nf][e] = pv;
          s4[e] += pv;
        }
      l_lane[mi] += s4[0] + s4[1] + s4[2] + s4[3];
#pragma unroll
      for (int ks = 0; ks < 2; ++ks) {
        bf16x8 t;
#pragma unroll
        for (int e = 0; e < 4; ++e) {
          t[e] = (bf16)sf[mi][2 * ks][e];
          t[4 + e] = (bf16)sf[mi][2 * ks + 1][e];
        }
        pa[mi][ks] = t;
      }
    }

    // ---- PV ----
    __builtin_amdgcn_s_setprio(1);
#pragma unroll
    for (int nd = 0; nd < 4; ++nd)
#pragma unroll
      for (int ks = 0; ks < 2; ++ks) {
        int dd = nd * 16 + r;
        int boff = (dd * 128 + ks * 64 + hq * 16) ^ ((dd & 7) << 4);
        bf16x8 vv = *(const bf16x8*)((const char*)&sV[cur][0] + boff);
#pragma unroll
        for (int mi = 0; mi < 2; ++mi)
          o[mi][nd] = MFMA16(pa[mi][ks], vv, o[mi][nd]);
      }
    __builtin_amdgcn_s_setprio(0);

    if (kt + 1 < S_ / KVB) writeV(cur ^ 1);
    __syncthreads();
    cur ^= 1;
  }

  // ---- epilogue ----
  const int b = bh >> 4, h = bh & 15;
  float lq[2][4];
#pragma unroll
  for (int mi = 0; mi < 2; ++mi) {
    float lr = l_lane[mi];
    lr += __shfl_xor(lr, 16);
    lr += __shfl_xor(lr, 32);
    int lb = __builtin_bit_cast(int, lr);
#pragma unroll
    for (int j = 0; j < 4; ++j) {
      int g = __builtin_amdgcn_ds_bpermute((hq * 4 + j) * 4, lb);
      lq[mi][j] = __builtin_bit_cast(float, g);
    }
  }
#pragma unroll
  for (int mi = 0; mi < 2; ++mi)
#pragma unroll
    for (int nd = 0; nd < 4; ++nd)
#pragma unroll
      for (int j = 0; j < 4; ++j) {
        int s = q0 + mi * 16 + hq * 4 + j;
        int d = nd * 16 + r;
        float ov = o[mi][nd][j] / lq[mi][j];
        bf16 hv = (bf16)ov;
        bf16 lv = (bf16)(ov - (float)hv);
        size_t idx = (((size_t)(b * S_ + s)) * H_ + h) * D_ + d;
        Ch[idx] = hv;
        Cl[idx] = lv;
      }
}

// ---------------- host ----------------
extern "C" void kernel_launch(void* const* d_in, const int* in_sizes, int n_in,
                              void* d_out, int out_size, void* d_ws, size_t ws_size,
                              hipStream_t stream) {
  const float* x = (const float*)d_in[0];
  const int* pos = (const int*)d_in[1];
  const float* Wq = (const float*)d_in[2];
  const float* bq = (const float*)d_in[3];
  const float* Wk = (const float*)d_in[4];
  const float* bk = (const float*)d_in[5];
  const float* Wv = (const float*)d_in[6];
  const float* bv = (const float*)d_in[7];
  const float* Wo = (const float*)d_in[8];
  const float* bo = (const float*)d_in[9];
  float* out = (float*)d_out;

  char* p = (char*)d_ws;
  auto alloc = [&](size_t bytes) {
    char* rp = p;
    p += (bytes + 255) & ~(size_t)255;
    return rp;
  };
  const size_t XB = (size_t)M_ * E_ * sizeof(bf16);        // 8 MiB
  const size_t WB = (size_t)E_ * E_ * sizeof(bf16);        // 2 MiB
  const size_t TB = (size_t)B_ * S_ * NT2 * sizeof(float); // 256 KiB
  bf16* Xh = (bf16*)alloc(XB);
  bf16* Xl = (bf16*)alloc(XB);
  bf16* WqTh = (bf16*)alloc(WB); bf16* WqTl = (bf16*)alloc(WB);
  bf16* WkTh = (bf16*)alloc(WB); bf16* WkTl = (bf16*)alloc(WB);
  bf16* WvTh = (bf16*)alloc(WB); bf16* WvTl = (bf16*)alloc(WB);
  bf16* WoTh = (bf16*)alloc(WB); bf16* WoTl = (bf16*)alloc(WB);
  float* cosT = (float*)alloc(TB);
  float* sinT = (float*)alloc(TB);
  bf16* Qh = (bf16*)alloc(XB); bf16* Qlo = (bf16*)alloc(XB);
  bf16* Kh = (bf16*)alloc(XB); bf16* Klo = (bf16*)alloc(XB);
  bf16* VTb = (bf16*)alloc(XB);
  // ctx aliases X (X is dead after the QKV GEMM; attn runs after on same stream)
  bf16* Ch = Xh;
  bf16* Cl = Xl;

  split_f32_kernel<<<M_ * E_ / 4 / 256, 256, 0, stream>>>(x, Xh, Xl, M_ * E_ / 4);
  dim3 tg(32, 32, 4);
  transpose_split4_kernel<<<tg, 256, 0, stream>>>(Wq, Wk, Wv, Wo, WqTh, WqTl,
                                                  WkTh, WkTl, WvTh, WvTl, WoTh,
                                                  WoTl);
  rope_tab_kernel<<<B_ * S_ * NT2 / 256, 256, 0, stream>>>(pos, cosT, sinT);

  dim3 gq(24, 32);
  gemm_qkv_kernel<<<gq, 512, 0, stream>>>(Xh, Xl, WqTh, WqTl, WkTh, WkTl, WvTh,
                                          WvTl, bq, bk, bv, cosT, sinT, Qh, Qlo,
                                          Kh, Klo, VTb);

  attn_kernel<<<B_ * H_ * (S_ / 128), 256, 0, stream>>>(Qh, Qlo, Kh, Klo, VTb,
                                                        Ch, Cl);

  dim3 go(8, 32);
  gemm_o_kernel<<<go, 512, 0, stream>>>(Ch, Cl, WoTh, WoTl, bo, out);
}

// Round 11
// 237.738 us; speedup vs baseline: 1.2315x; 1.0113x over previous
//
#include <hip/hip_runtime.h>
#include <hip/hip_bf16.h>
#include <math.h>

#define B_ 2
#define S_ 2048
#define E_ 1024
#define H_ 16
#define D_ 64
#define M_ 4096   // B_*S_
#define NT2 32    // D_/2
#define KVB 64

typedef __bf16 bf16;
typedef __bf16 bf16x4 __attribute__((ext_vector_type(4)));
typedef __bf16 bf16x8 __attribute__((ext_vector_type(8)));
typedef float f32x4 __attribute__((ext_vector_type(4)));
typedef float f32x16 __attribute__((ext_vector_type(16)));

__device__ __forceinline__ void gload_lds16(const void* g, void* lds) {
  __builtin_amdgcn_global_load_lds(
      (const __attribute__((address_space(1))) unsigned int*)g,
      (__attribute__((address_space(3))) unsigned int*)lds, 16, 0, 0);
}

#define MFMA16(a, b, c) __builtin_amdgcn_mfma_f32_16x16x32_bf16(a, b, c, 0, 0, 0)
#define MFMA32(a, b, c) __builtin_amdgcn_mfma_f32_32x32x16_bf16(a, b, c, 0, 0, 0)

// ---------------- split fp32 -> bf16 hi/lo ----------------
__global__ __launch_bounds__(256)
void split_f32_kernel(const float* __restrict__ in, bf16* __restrict__ hi,
                      bf16* __restrict__ lo, int n4) {
  int i = blockIdx.x * 256 + threadIdx.x;
  if (i >= n4) return;
  float4 v = ((const float4*)in)[i];
  bf16 h0 = (bf16)v.x, h1 = (bf16)v.y, h2 = (bf16)v.z, h3 = (bf16)v.w;
  bf16x4 hv = {h0, h1, h2, h3};
  bf16x4 lv = {(bf16)(v.x - (float)h0), (bf16)(v.y - (float)h1),
               (bf16)(v.z - (float)h2), (bf16)(v.w - (float)h3)};
  *(bf16x4*)(hi + 4 * (size_t)i) = hv;
  *(bf16x4*)(lo + 4 * (size_t)i) = lv;
}

// ------------- transpose + split, all 4 weights in one launch -------------
__global__ __launch_bounds__(256)
void transpose_split4_kernel(const float* __restrict__ Wq, const float* __restrict__ Wk,
                             const float* __restrict__ Wv, const float* __restrict__ Wo,
                             bf16* __restrict__ Tqh, bf16* __restrict__ Tql,
                             bf16* __restrict__ Tkh, bf16* __restrict__ Tkl,
                             bf16* __restrict__ Tvh, bf16* __restrict__ Tvl,
                             bf16* __restrict__ Toh, bf16* __restrict__ Tol) {
  const int z = blockIdx.z;
  const float* W = z == 0 ? Wq : z == 1 ? Wk : z == 2 ? Wv : Wo;
  bf16* Th = z == 0 ? Tqh : z == 1 ? Tkh : z == 2 ? Tvh : Toh;
  bf16* Tl = z == 0 ? Tql : z == 1 ? Tkl : z == 2 ? Tvl : Tol;
  __shared__ float tile[32][33];
  const int tx = threadIdx.x & 31, ty = threadIdx.x >> 5;  // ty 0..7
  const int c0 = blockIdx.x * 32, r0 = blockIdx.y * 32;
#pragma unroll
  for (int i = 0; i < 4; ++i)
    tile[ty + 8 * i][tx] = W[(size_t)(r0 + ty + 8 * i) * E_ + c0 + tx];
  __syncthreads();
#pragma unroll
  for (int i = 0; i < 4; ++i) {
    int rr = ty + 8 * i;
    float v = tile[tx][rr];  // = W[r0+tx][c0+rr]
    bf16 hv = (bf16)v;
    size_t oidx = (size_t)(c0 + rr) * E_ + r0 + tx;
    Th[oidx] = hv;
    Tl[oidx] = (bf16)(v - (float)hv);
  }
}

// ---------------- RoPE cos/sin table ----------------
__global__ __launch_bounds__(256)
void rope_tab_kernel(const int* __restrict__ pos, float* __restrict__ cosT,
                     float* __restrict__ sinT) {
  int idx = blockIdx.x * 256 + threadIdx.x;  // B_*S_*NT2
  int t = idx & 31, bs = idx >> 5;
  double th = pow(10000.0, -(double)(2 * t) / 64.0);
  float ang = (float)pos[bs] * (float)th;  // fp32 product (matches ref rounding)
  double a = (double)ang;
  cosT[idx] = (float)cos(a);
  sinT[idx] = (float)sin(a);
}

// ---------------- fused QKV split-bf16 GEMM, 128^2, 8 waves ----------------
// r10's winning structure (single-buffer, BK=32, 8 waves 2Mx4N, 2 blocks/CU)
// with the LDS layout changed to the attn kernel's ZERO-conflict pattern:
// hi/lo pairs merged into one [128 rows][128B] buffer (row = [h:64B|l:64B],
// 8 16B-slots) swizzled byte ^= (row&7)<<4 — replaces the 64B-row 4-slot
// layout whose residual aliasing measured ~9.4e6 conflict cycles (~13%).
// Both-sides rule: linear LDS dest, pre-swizzled global source, XOR on read.
#define BMg 128
#define BNg 128
#define BKg 32

__global__ __launch_bounds__(512, 4)
void gemm_qkv_kernel(const bf16* __restrict__ Ah_g, const bf16* __restrict__ Al_g,
                     const bf16* __restrict__ BhQ, const bf16* __restrict__ BlQ,
                     const bf16* __restrict__ BhK, const bf16* __restrict__ BlK,
                     const bf16* __restrict__ BhV, const bf16* __restrict__ BlV,
                     const float* __restrict__ bqp, const float* __restrict__ bkp,
                     const float* __restrict__ bvp,
                     const float* __restrict__ cosT, const float* __restrict__ sinT,
                     bf16* __restrict__ Qh, bf16* __restrict__ Qlo,
                     bf16* __restrict__ Kh, bf16* __restrict__ Klo,
                     bf16* __restrict__ VTb) {
  __shared__ bf16 lA[BMg * 64];  // 16 KB: row = [Ah 32 bf16 | Al 32 bf16]
  __shared__ bf16 lB[BNg * 64];  // 16 KB
  const int tid = threadIdx.x;        // 0..511
  const int nb = blockIdx.x;          // 0..23
  const int third = nb >> 3;          // 0=Q 1=K 2=V
  const int n0 = (nb & 7) * BNg;
  const int m0 = blockIdx.y * BMg;
  const bf16* Bh_g = third == 0 ? BhQ : third == 1 ? BhK : BhV;
  const bf16* Bl_g = third == 0 ? BlQ : third == 1 ? BlK : BlV;
  const float* bias = third == 0 ? bqp : third == 1 ? bkp : bvp;
  const int wave = tid >> 6, lane = tid & 63;
  const int wr = wave >> 2, wc = wave & 3;  // 2M x 4N wave grid
  const int r = lane & 31, half = lane >> 5;
  const int KD = 1024;

  f32x16 acc[2] = {};  // mi = 0,1 (rows wr*64+mi*32); single 32-col block

  for (int kt = 0; kt < KD / BKg; ++kt) {
    const int k0 = kt * BKg;
    {
#pragma unroll
      for (int i = 0; i < 2; ++i) {
        int c = i * 512 + tid;          // 16B chunk 0..1023
        int row = c >> 3, u = c & 7;
        int us = u ^ (row & 7);         // pre-swizzled source slot
        int uu = us & 3;
        char* lpA = (char*)lA + (size_t)(i * 512 + wave * 64) * 16;
        char* lpB = (char*)lB + (size_t)(i * 512 + wave * 64) * 16;
        const bf16* sA = (us < 4) ? Ah_g : Al_g;
        const bf16* sB = (us < 4) ? Bh_g : Bl_g;
        gload_lds16((const char*)(sA + (size_t)(m0 + row) * KD + k0) + uu * 16,
                    lpA);
        gload_lds16((const char*)(sB + (size_t)(n0 + row) * KD + k0) + uu * 16,
                    lpB);
      }
    }
    __syncthreads();
#pragma unroll
    for (int ks = 0; ks < 2; ++ks) {
      bf16x8 a_h[2], a_l[2], b_h, b_l;
#pragma unroll
      for (int mi = 0; mi < 2; ++mi) {
        int row = wr * 64 + mi * 32 + r;
        int sw = (row & 7) << 4;
        const char* base = (const char*)lA + row * 128;
        a_h[mi] = *(const bf16x8*)(base + ((ks * 32 + half * 16) ^ sw));
        a_l[mi] = *(const bf16x8*)(base + ((64 + ks * 32 + half * 16) ^ sw));
      }
      {
        int row = wc * 32 + r;
        int sw = (row & 7) << 4;
        const char* base = (const char*)lB + row * 128;
        b_h = *(const bf16x8*)(base + ((ks * 32 + half * 16) ^ sw));
        b_l = *(const bf16x8*)(base + ((64 + ks * 32 + half * 16) ^ sw));
      }
      __builtin_amdgcn_s_setprio(1);
#pragma unroll
      for (int mi = 0; mi < 2; ++mi) {
        acc[mi] = MFMA32(a_h[mi], b_h, acc[mi]);
        acc[mi] = MFMA32(a_h[mi], b_l, acc[mi]);
        acc[mi] = MFMA32(a_l[mi], b_h, acc[mi]);
      }
      __builtin_amdgcn_s_setprio(0);
    }
    __syncthreads();
  }

  // ---- epilogue ----
#pragma unroll
  for (int mi = 0; mi < 2; ++mi) {
    const int gcol = n0 + wc * 32 + r;
    const float bv = bias[gcol];
    if (third < 2) {  // Q or K: RoPE (+scale for Q), split
      bf16* outH = third == 0 ? Qh : Kh;
      bf16* outL = third == 0 ? Qlo : Klo;
      const int h = gcol >> 6, d = gcol & 63, tt = d >> 1;
#pragma unroll
      for (int tq = 0; tq < 4; ++tq) {
#pragma unroll
        for (int u = 0; u < 4; ++u) {
          int reg = tq * 4 + u;
          int grow = m0 + wr * 64 + mi * 32 + (u + 8 * tq + 4 * half);
          int s = grow & (S_ - 1), b = grow >> 11;
          float v = acc[mi][reg] + bv;
          float other = __shfl_xor(v, 1);  // partner dim (d^1), lane^1
          float cs = cosT[(size_t)(b * S_ + s) * NT2 + tt];
          float sn = sinT[(size_t)(b * S_ + s) * NT2 + tt];
          float vr = (d & 1) ? (other * sn + v * cs) : (v * cs - other * sn);
          if (third == 0) vr *= 0.125f;  // 1/sqrt(D)
          bf16 hv = (bf16)vr;
          bf16 lv = (bf16)(vr - (float)hv);
          size_t idx = (((size_t)(b * H_ + h)) * S_ + s) * D_ + d;
          outH[idx] = hv;
          outL[idx] = lv;
        }
      }
    } else {  // V: bf16, transposed [B,H,D,S]
      const int h = gcol >> 6, d = gcol & 63;
#pragma unroll
      for (int tq = 0; tq < 4; ++tq) {
        int grow = m0 + wr * 64 + mi * 32 + (8 * tq + 4 * half);
        int s = grow & (S_ - 1), b = grow >> 11;
        ushort4 pk;
        unsigned short* pp = (unsigned short*)&pk;
#pragma unroll
        for (int u = 0; u < 4; ++u) {
          float v = acc[mi][tq * 4 + u] + bv;
          bf16 hv = (bf16)v;
          pp[u] = __builtin_bit_cast(unsigned short, hv);
        }
        *(ushort4*)((unsigned short*)VTb +
                    (((size_t)(b * H_ + h)) * D_ + d) * S_ + s) = pk;
      }
    }
  }
}

// ---------------- O-projection split-bf16 GEMM (128^2, 8 waves) ------------
__global__ __launch_bounds__(512, 4)
void gemm_o_kernel(const bf16* __restrict__ Ah_g, const bf16* __restrict__ Al_g,
                   const bf16* __restrict__ Bh_g, const bf16* __restrict__ Bl_g,
                   const float* __restrict__ bias, float* __restrict__ outF) {
  __shared__ bf16 lA[BMg * 64];
  __shared__ bf16 lB[BNg * 64];
  const int tid = threadIdx.x;
  const int m0 = blockIdx.y * BMg, n0 = blockIdx.x * BNg;
  const int wave = tid >> 6, lane = tid & 63;
  const int wr = wave >> 2, wc = wave & 3;
  const int r = lane & 31, half = lane >> 5;
  const int KD = 1024;

  f32x16 acc[2] = {};

  for (int kt = 0; kt < KD / BKg; ++kt) {
    const int k0 = kt * BKg;
    {
#pragma unroll
      for (int i = 0; i < 2; ++i) {
        int c = i * 512 + tid;
        int row = c >> 3, u = c & 7;
        int us = u ^ (row & 7);
        int uu = us & 3;
        char* lpA = (char*)lA + (size_t)(i * 512 + wave * 64) * 16;
        char* lpB = (char*)lB + (size_t)(i * 512 + wave * 64) * 16;
        const bf16* sA = (us < 4) ? Ah_g : Al_g;
        const bf16* sB = (us < 4) ? Bh_g : Bl_g;
        gload_lds16((const char*)(sA + (size_t)(m0 + row) * KD + k0) + uu * 16,
                    lpA);
        gload_lds16((const char*)(sB + (size_t)(n0 + row) * KD + k0) + uu * 16,
                    lpB);
      }
    }
    __syncthreads();
#pragma unroll
    for (int ks = 0; ks < 2; ++ks) {
      bf16x8 a_h[2], a_l[2], b_h, b_l;
#pragma unroll
      for (int mi = 0; mi < 2; ++mi) {
        int row = wr * 64 + mi * 32 + r;
        int sw = (row & 7) << 4;
        const char* base = (const char*)lA + row * 128;
        a_h[mi] = *(const bf16x8*)(base + ((ks * 32 + half * 16) ^ sw));
        a_l[mi] = *(const bf16x8*)(base + ((64 + ks * 32 + half * 16) ^ sw));
      }
      {
        int row = wc * 32 + r;
        int sw = (row & 7) << 4;
        const char* base = (const char*)lB + row * 128;
        b_h = *(const bf16x8*)(base + ((ks * 32 + half * 16) ^ sw));
        b_l = *(const bf16x8*)(base + ((64 + ks * 32 + half * 16) ^ sw));
      }
      __builtin_amdgcn_s_setprio(1);
#pragma unroll
      for (int mi = 0; mi < 2; ++mi) {
        acc[mi] = MFMA32(a_h[mi], b_h, acc[mi]);
        acc[mi] = MFMA32(a_h[mi], b_l, acc[mi]);
        acc[mi] = MFMA32(a_l[mi], b_h, acc[mi]);
      }
      __builtin_amdgcn_s_setprio(0);
    }
    __syncthreads();
  }

#pragma unroll
  for (int mi = 0; mi < 2; ++mi) {
    const int gcol = n0 + wc * 32 + r;
    const float bv = bias[gcol];
#pragma unroll
    for (int tq = 0; tq < 4; ++tq)
#pragma unroll
      for (int u = 0; u < 4; ++u) {
        int grow = m0 + wr * 64 + mi * 32 + (u + 8 * tq + 4 * half);
        outF[(size_t)grow * E_ + gcol] = acc[mi][tq * 4 + u] + bv;
      }
  }
}

// ---------------- flash attention (in-register softmax, swapped QK^T) -------
// setprio REVERTED (r10 regression suspect: 4-wave barrier-synced blocks are
// m190's lockstep case, where setprio measured negative).
__global__ __launch_bounds__(256)
void attn_kernel(const bf16* __restrict__ Qh, const bf16* __restrict__ Ql,
                 const bf16* __restrict__ Kh, const bf16* __restrict__ Kl,
                 const bf16* __restrict__ VT, bf16* __restrict__ Ch,
                 bf16* __restrict__ Cl) {
  __shared__ bf16 sKh[2][KVB * 64];
  __shared__ bf16 sKl[2][KVB * 64];
  __shared__ bf16 sV[2][KVB * 64];  // [d=64][key-pos=64], row-XOR-swizzled

  const int tid = threadIdx.x;
  const int wave = tid >> 6, lane = tid & 63;
  const int r = lane & 15, hq = lane >> 4;
  const int bid = blockIdx.x;
  const int swz = (bid & 7) * 64 + (bid >> 3);  // XCD-chunked (512 % 8 == 0)
  const int bh = swz >> 4, qblk = swz & 15;
  const int q0 = qblk * 128 + wave * 32;
  const size_t hb = (size_t)bh * (S_ * D_);
  const size_t vb = (size_t)bh * (D_ * S_);

  bf16x8 qh[2][2], ql[2][2];
#pragma unroll
  for (int mi = 0; mi < 2; ++mi)
#pragma unroll
    for (int ks = 0; ks < 2; ++ks) {
      size_t off = hb + (size_t)(q0 + mi * 16 + r) * D_ + ks * 32 + hq * 8;
      qh[mi][ks] = *(const bf16x8*)&Qh[off];
      ql[mi][ks] = *(const bf16x8*)&Ql[off];
    }

  float m_lane[2] = {-1e30f, -1e30f};
  float l_lane[2] = {0.f, 0.f};
  f32x4 o[2][4] = {};

  auto stageK = [&](int kt, int buf) {
    const bf16* kbh = Kh + hb + (size_t)kt * (KVB * D_);
    const bf16* kbl = Kl + hb + (size_t)kt * (KVB * D_);
#pragma unroll
    for (int i = 0; i < 2; ++i) {
      int c = i * 256 + tid;
      int ldo = (i * 256 + wave * 64) * 16;
      int cs = c ^ ((c >> 3) & 7);
      gload_lds16(kbh + cs * 8, (char*)&sKh[buf][0] + ldo);
      gload_lds16(kbl + cs * 8, (char*)&sKl[buf][0] + ldo);
    }
  };
  uint4 vld[2];
  auto loadV = [&](int kt) {
    const bf16* vbp = VT + vb + kt * KVB;
#pragma unroll
    for (int i = 0; i < 2; ++i) {
      int c = i * 256 + tid;
      int row = c >> 3, w = c & 7;
      vld[i] = *(const uint4*)(vbp + (size_t)row * S_ + w * 8);
    }
  };
  auto writeV = [&](int buf) {
#pragma unroll
    for (int i = 0; i < 2; ++i) {
      int c = i * 256 + tid;
      int row = c >> 3, w = c & 7;
      int pb0 = (w >> 2) * 32 + (w & 1) * 16 + ((w >> 1) & 1) * 4;
      char* base = (char*)&sV[buf][0] + row * 128;
      uint2 lo = {vld[i].x, vld[i].y};
      uint2 hi = {vld[i].z, vld[i].w};
      *(uint2*)(base + ((pb0 * 2) ^ ((row & 7) << 4))) = lo;
      *(uint2*)(base + (((pb0 + 8) * 2) ^ ((row & 7) << 4))) = hi;
    }
  };

  stageK(0, 0);
  loadV(0);
  writeV(0);
  __syncthreads();
  int cur = 0;

  for (int kt = 0; kt < S_ / KVB; ++kt) {
    if (kt + 1 < S_ / KVB) {
      stageK(kt + 1, cur ^ 1);
      loadV(kt + 1);
    }

    // ---- QK^T (swapped: A=K, B=Q) ----
    f32x4 sf[2][4] = {};
#pragma unroll
    for (int nf = 0; nf < 4; ++nf)
#pragma unroll
      for (int ks = 0; ks < 2; ++ks) {
        int kk = nf * 16 + r;
        int boff = (kk * 128 + ks * 64 + hq * 16) ^ ((kk & 7) << 4);
        bf16x8 kkh = *(const bf16x8*)((const char*)&sKh[cur][0] + boff);
        bf16x8 kkl = *(const bf16x8*)((const char*)&sKl[cur][0] + boff);
#pragma unroll
        for (int mi = 0; mi < 2; ++mi) {
          sf[mi][nf] = MFMA16(kkh, qh[mi][ks], sf[mi][nf]);
          sf[mi][nf] = MFMA16(kkh, ql[mi][ks], sf[mi][nf]);
          sf[mi][nf] = MFMA16(kkl, qh[mi][ks], sf[mi][nf]);
        }
      }

    // ---- defer-max online softmax (lane-local fast path) ----
    float lmax[2];
#pragma unroll
    for (int mi = 0; mi < 2; ++mi) {
      f32x4 m4;
#pragma unroll
      for (int e = 0; e < 4; ++e)
        m4[e] = fmaxf(fmaxf(sf[mi][0][e], sf[mi][1][e]),
                      fmaxf(sf[mi][2][e], sf[mi][3][e]));
      lmax[mi] = fmaxf(fmaxf(m4[0], m4[1]), fmaxf(m4[2], m4[3]));
    }
    int need = (lmax[0] > m_lane[0] + 8.f) || (lmax[1] > m_lane[1] + 8.f);
    if (__any(need)) {
#pragma unroll
      for (int mi = 0; mi < 2; ++mi) {
        float mx = lmax[mi];
        mx = fmaxf(mx, __shfl_xor(mx, 16));
        mx = fmaxf(mx, __shfl_xor(mx, 32));
        float mn = fmaxf(m_lane[mi], mx);
        float al = __expf(m_lane[mi] - mn);
        l_lane[mi] *= al;
        m_lane[mi] = mn;
        int alb = __builtin_bit_cast(int, al);
#pragma unroll
        for (int j = 0; j < 4; ++j) {
          int g = __builtin_amdgcn_ds_bpermute((hq * 4 + j) * 4, alb);
          float a = __builtin_bit_cast(float, g);
#pragma unroll
          for (int nd = 0; nd < 4; ++nd) o[mi][nd][j] *= a;
        }
      }
    }
    bf16x8 pa[2][2];
#pragma unroll
    for (int mi = 0; mi < 2; ++mi) {
      f32x4 s4 = {};
#pragma unroll
      for (int nf = 0; nf < 4; ++nf)
#pragma unroll
        for (int e = 0; e < 4; ++e) {
          float pv = __expf(sf[mi][nf][e] - m_lane[mi]);
          sf[mi][nf][e] = pv;
          s4[e] += pv;
        }
      l_lane[mi] += s4[0] + s4[1] + s4[2] + s4[3];
#pragma unroll
      for (int ks = 0; ks < 2; ++ks) {
        bf16x8 t;
#pragma unroll
        for (int e = 0; e < 4; ++e) {
          t[e] = (bf16)sf[mi][2 * ks][e];
          t[4 + e] = (bf16)sf[mi][2 * ks + 1][e];
        }
        pa[mi][ks] = t;
      }
    }

    // ---- PV ----
#pragma unroll
    for (int nd = 0; nd < 4; ++nd)
#pragma unroll
      for (int ks = 0; ks < 2; ++ks) {
        int dd = nd * 16 + r;
        int boff = (dd * 128 + ks * 64 + hq * 16) ^ ((dd & 7) << 4);
        bf16x8 vv = *(const bf16x8*)((const char*)&sV[cur][0] + boff);
#pragma unroll
        for (int mi = 0; mi < 2; ++mi)
          o[mi][nd] = MFMA16(pa[mi][ks], vv, o[mi][nd]);
      }

    if (kt + 1 < S_ / KVB) writeV(cur ^ 1);
    __syncthreads();
    cur ^= 1;
  }

  // ---- epilogue ----
  const int b = bh >> 4, h = bh & 15;
  float lq[2][4];
#pragma unroll
  for (int mi = 0; mi < 2; ++mi) {
    float lr = l_lane[mi];
    lr += __shfl_xor(lr, 16);
    lr += __shfl_xor(lr, 32);
    int lb = __builtin_bit_cast(int, lr);
#pragma unroll
    for (int j = 0; j < 4; ++j) {
      int g = __builtin_amdgcn_ds_bpermute((hq * 4 + j) * 4, lb);
      lq[mi][j] = __builtin_bit_cast(float, g);
    }
  }
#pragma unroll
  for (int mi = 0; mi < 2; ++mi)
#pragma unroll
    for (int nd = 0; nd < 4; ++nd)
#pragma unroll
      for (int j = 0; j < 4; ++j) {
        int s = q0 + mi * 16 + hq * 4 + j;
        int d = nd * 16 + r;
        float ov = o[mi][nd][j] / lq[mi][j];
        bf16 hv = (bf16)ov;
        bf16 lv = (bf16)(ov - (float)hv);
        size_t idx = (((size_t)(b * S_ + s)) * H_ + h) * D_ + d;
        Ch[idx] = hv;
        Cl[idx] = lv;
      }
}

// ---------------- host ----------------
extern "C" void kernel_launch(void* const* d_in, const int* in_sizes, int n_in,
                              void* d_out, int out_size, void* d_ws, size_t ws_size,
                              hipStream_t stream) {
  const float* x = (const float*)d_in[0];
  const int* pos = (const int*)d_in[1];
  const float* Wq = (const float*)d_in[2];
  const float* bq = (const float*)d_in[3];
  const float* Wk = (const float*)d_in[4];
  const float* bk = (const float*)d_in[5];
  const float* Wv = (const float*)d_in[6];
  const float* bv = (const float*)d_in[7];
  const float* Wo = (const float*)d_in[8];
  const float* bo = (const float*)d_in[9];
  float* out = (float*)d_out;

  char* p = (char*)d_ws;
  auto alloc = [&](size_t bytes) {
    char* rp = p;
    p += (bytes + 255) & ~(size_t)255;
    return rp;
  };
  const size_t XB = (size_t)M_ * E_ * sizeof(bf16);        // 8 MiB
  const size_t WB = (size_t)E_ * E_ * sizeof(bf16);        // 2 MiB
  const size_t TB = (size_t)B_ * S_ * NT2 * sizeof(float); // 256 KiB
  bf16* Xh = (bf16*)alloc(XB);
  bf16* Xl = (bf16*)alloc(XB);
  bf16* WqTh = (bf16*)alloc(WB); bf16* WqTl = (bf16*)alloc(WB);
  bf16* WkTh = (bf16*)alloc(WB); bf16* WkTl = (bf16*)alloc(WB);
  bf16* WvTh = (bf16*)alloc(WB); bf16* WvTl = (bf16*)alloc(WB);
  bf16* WoTh = (bf16*)alloc(WB); bf16* WoTl = (bf16*)alloc(WB);
  float* cosT = (float*)alloc(TB);
  float* sinT = (float*)alloc(TB);
  bf16* Qh = (bf16*)alloc(XB); bf16* Qlo = (bf16*)alloc(XB);
  bf16* Kh = (bf16*)alloc(XB); bf16* Klo = (bf16*)alloc(XB);
  bf16* VTb = (bf16*)alloc(XB);
  // ctx aliases X (X is dead after the QKV GEMM; attn runs after on same stream)
  bf16* Ch = Xh;
  bf16* Cl = Xl;

  split_f32_kernel<<<M_ * E_ / 4 / 256, 256, 0, stream>>>(x, Xh, Xl, M_ * E_ / 4);
  dim3 tg(32, 32, 4);
  transpose_split4_kernel<<<tg, 256, 0, stream>>>(Wq, Wk, Wv, Wo, WqTh, WqTl,
                                                  WkTh, WkTl, WvTh, WvTl, WoTh,
                                                  WoTl);
  rope_tab_kernel<<<B_ * S_ * NT2 / 256, 256, 0, stream>>>(pos, cosT, sinT);

  dim3 gq(24, 32);
  gemm_qkv_kernel<<<gq, 512, 0, stream>>>(Xh, Xl, WqTh, WqTl, WkTh, WkTl, WvTh,
                                          WvTl, bq, bk, bv, cosT, sinT, Qh, Qlo,
                                          Kh, Klo, VTb);

  attn_kernel<<<B_ * H_ * (S_ / 128), 256, 0, stream>>>(Qh, Qlo, Kh, Klo, VTb,
                                                        Ch, Cl);

  dim3 go(8, 32);
  gemm_o_kernel<<<go, 512, 0, stream>>>(Ch, Cl, WoTh, WoTl, bo, out);
}

// Round 12
// 228.667 us; speedup vs baseline: 1.2804x; 1.0397x over previous
//
#include <hip/hip_runtime.h>
#include <hip/hip_bf16.h>
#include <math.h>

#define B_ 2
#define S_ 2048
#define E_ 1024
#define H_ 16
#define D_ 64
#define M_ 4096   // B_*S_
#define NT2 32    // D_/2
#define KVB 64

typedef __bf16 bf16;
typedef __bf16 bf16x4 __attribute__((ext_vector_type(4)));
typedef __bf16 bf16x8 __attribute__((ext_vector_type(8)));
typedef float f32x4 __attribute__((ext_vector_type(4)));
typedef float f32x16 __attribute__((ext_vector_type(16)));

__device__ __forceinline__ void gload_lds16(const void* g, void* lds) {
  __builtin_amdgcn_global_load_lds(
      (const __attribute__((address_space(1))) unsigned int*)g,
      (__attribute__((address_space(3))) unsigned int*)lds, 16, 0, 0);
}

#define MFMA16(a, b, c) __builtin_amdgcn_mfma_f32_16x16x32_bf16(a, b, c, 0, 0, 0)
#define MFMA32(a, b, c) __builtin_amdgcn_mfma_f32_32x32x16_bf16(a, b, c, 0, 0, 0)

// ---------------- fused prep: split X + transpose/split 4 W + rope table ----
// 1D grid, range-dispatched: [0,4096) split, [4096,8192) transpose, [8192,8704) rope
__global__ __launch_bounds__(256)
void prep_kernel(const float* __restrict__ x, const int* __restrict__ pos,
                 const float* __restrict__ Wq, const float* __restrict__ Wk,
                 const float* __restrict__ Wv, const float* __restrict__ Wo,
                 bf16* __restrict__ Xh, bf16* __restrict__ Xl,
                 bf16* __restrict__ Tqh, bf16* __restrict__ Tql,
                 bf16* __restrict__ Tkh, bf16* __restrict__ Tkl,
                 bf16* __restrict__ Tvh, bf16* __restrict__ Tvl,
                 bf16* __restrict__ Toh, bf16* __restrict__ Tol,
                 float* __restrict__ cosT, float* __restrict__ sinT) {
  const int bid = blockIdx.x;
  if (bid < 4096) {  // ---- split fp32 -> bf16 hi/lo (float4 per thread) ----
    int i = bid * 256 + threadIdx.x;
    float4 v = ((const float4*)x)[i];
    bf16 h0 = (bf16)v.x, h1 = (bf16)v.y, h2 = (bf16)v.z, h3 = (bf16)v.w;
    bf16x4 hv = {h0, h1, h2, h3};
    bf16x4 lv = {(bf16)(v.x - (float)h0), (bf16)(v.y - (float)h1),
                 (bf16)(v.z - (float)h2), (bf16)(v.w - (float)h3)};
    *(bf16x4*)(Xh + 4 * (size_t)i) = hv;
    *(bf16x4*)(Xl + 4 * (size_t)i) = lv;
  } else if (bid < 8192) {  // ---- transpose + split one 32x32 W tile ----
    int t = bid - 4096;
    int z = t >> 10, rem = t & 1023;
    int bx = rem & 31, by = rem >> 5;
    const float* W = z == 0 ? Wq : z == 1 ? Wk : z == 2 ? Wv : Wo;
    bf16* Th = z == 0 ? Tqh : z == 1 ? Tkh : z == 2 ? Tvh : Toh;
    bf16* Tl = z == 0 ? Tql : z == 1 ? Tkl : z == 2 ? Tvl : Tol;
    __shared__ float tile[32][33];
    const int tx = threadIdx.x & 31, ty = threadIdx.x >> 5;  // ty 0..7
    const int c0 = bx * 32, r0 = by * 32;
#pragma unroll
    for (int i = 0; i < 4; ++i)
      tile[ty + 8 * i][tx] = W[(size_t)(r0 + ty + 8 * i) * E_ + c0 + tx];
    __syncthreads();
#pragma unroll
    for (int i = 0; i < 4; ++i) {
      int rr = ty + 8 * i;
      float v = tile[tx][rr];  // = W[r0+tx][c0+rr]
      bf16 hv = (bf16)v;
      size_t oidx = (size_t)(c0 + rr) * E_ + r0 + tx;
      Th[oidx] = hv;
      Tl[oidx] = (bf16)(v - (float)hv);
    }
  } else {  // ---- RoPE cos/sin table ----
    int idx = (bid - 8192) * 256 + threadIdx.x;  // B_*S_*NT2
    int t = idx & 31, bs = idx >> 5;
    double th = pow(10000.0, -(double)(2 * t) / 64.0);
    float ang = (float)pos[bs] * (float)th;  // fp32 product (matches ref)
    double a = (double)ang;
    cosT[idx] = (float)cos(a);
    sinT[idx] = (float)sin(a);
  }
}

// ---------------- fused QKV split-bf16 GEMM, 128^2, 8 waves ----------------
// r10/r11 winning structure (single-buffer, BK=32, 8 waves 2Mx4N, merged
// [row][h64B|l64B] LDS, swizzle byte^=(row&7)<<4 both-sides).  NEW: the
// a_l*b_h term accumulates into a SECOND accumulator -> 4 independent MFMA
// dep chains (max len 4) instead of 2 chains of 6; summed in epilogue.
#define BMg 128
#define BNg 128
#define BKg 32

__global__ __launch_bounds__(512, 4)
void gemm_qkv_kernel(const bf16* __restrict__ Ah_g, const bf16* __restrict__ Al_g,
                     const bf16* __restrict__ BhQ, const bf16* __restrict__ BlQ,
                     const bf16* __restrict__ BhK, const bf16* __restrict__ BlK,
                     const bf16* __restrict__ BhV, const bf16* __restrict__ BlV,
                     const float* __restrict__ bqp, const float* __restrict__ bkp,
                     const float* __restrict__ bvp,
                     const float* __restrict__ cosT, const float* __restrict__ sinT,
                     bf16* __restrict__ Qh, bf16* __restrict__ Qlo,
                     bf16* __restrict__ Kh, bf16* __restrict__ Klo,
                     bf16* __restrict__ VTb) {
  __shared__ bf16 lA[BMg * 64];  // 16 KB: row = [Ah 32 bf16 | Al 32 bf16]
  __shared__ bf16 lB[BNg * 64];  // 16 KB
  const int tid = threadIdx.x;        // 0..511
  const int nb = blockIdx.x;          // 0..23
  const int third = nb >> 3;          // 0=Q 1=K 2=V
  const int n0 = (nb & 7) * BNg;
  const int m0 = blockIdx.y * BMg;
  const bf16* Bh_g = third == 0 ? BhQ : third == 1 ? BhK : BhV;
  const bf16* Bl_g = third == 0 ? BlQ : third == 1 ? BlK : BlV;
  const float* bias = third == 0 ? bqp : third == 1 ? bkp : bvp;
  const int wave = tid >> 6, lane = tid & 63;
  const int wr = wave >> 2, wc = wave & 3;  // 2M x 4N wave grid
  const int r = lane & 31, half = lane >> 5;
  const int KD = 1024;

  f32x16 acc[2] = {};   // a_h*b_h and a_h*b_l terms
  f32x16 acc2[2] = {};  // a_l*b_h term (independent chain)

  for (int kt = 0; kt < KD / BKg; ++kt) {
    const int k0 = kt * BKg;
    {
#pragma unroll
      for (int i = 0; i < 2; ++i) {
        int c = i * 512 + tid;          // 16B chunk 0..1023
        int row = c >> 3, u = c & 7;
        int us = u ^ (row & 7);         // pre-swizzled source slot
        int uu = us & 3;
        char* lpA = (char*)lA + (size_t)(i * 512 + wave * 64) * 16;
        char* lpB = (char*)lB + (size_t)(i * 512 + wave * 64) * 16;
        const bf16* sA = (us < 4) ? Ah_g : Al_g;
        const bf16* sB = (us < 4) ? Bh_g : Bl_g;
        gload_lds16((const char*)(sA + (size_t)(m0 + row) * KD + k0) + uu * 16,
                    lpA);
        gload_lds16((const char*)(sB + (size_t)(n0 + row) * KD + k0) + uu * 16,
                    lpB);
      }
    }
    __syncthreads();
#pragma unroll
    for (int ks = 0; ks < 2; ++ks) {
      bf16x8 a_h[2], a_l[2], b_h, b_l;
#pragma unroll
      for (int mi = 0; mi < 2; ++mi) {
        int row = wr * 64 + mi * 32 + r;
        int sw = (row & 7) << 4;
        const char* base = (const char*)lA + row * 128;
        a_h[mi] = *(const bf16x8*)(base + ((ks * 32 + half * 16) ^ sw));
        a_l[mi] = *(const bf16x8*)(base + ((64 + ks * 32 + half * 16) ^ sw));
      }
      {
        int row = wc * 32 + r;
        int sw = (row & 7) << 4;
        const char* base = (const char*)lB + row * 128;
        b_h = *(const bf16x8*)(base + ((ks * 32 + half * 16) ^ sw));
        b_l = *(const bf16x8*)(base + ((64 + ks * 32 + half * 16) ^ sw));
      }
      __builtin_amdgcn_s_setprio(1);
#pragma unroll
      for (int mi = 0; mi < 2; ++mi) {
        acc[mi] = MFMA32(a_h[mi], b_h, acc[mi]);
        acc[mi] = MFMA32(a_h[mi], b_l, acc[mi]);
        acc2[mi] = MFMA32(a_l[mi], b_h, acc2[mi]);
      }
      __builtin_amdgcn_s_setprio(0);
    }
    __syncthreads();
  }

  // ---- epilogue ----
#pragma unroll
  for (int mi = 0; mi < 2; ++mi) {
    const int gcol = n0 + wc * 32 + r;
    const float bv = bias[gcol];
    if (third < 2) {  // Q or K: RoPE (+scale for Q), split
      bf16* outH = third == 0 ? Qh : Kh;
      bf16* outL = third == 0 ? Qlo : Klo;
      const int h = gcol >> 6, d = gcol & 63, tt = d >> 1;
#pragma unroll
      for (int tq = 0; tq < 4; ++tq) {
#pragma unroll
        for (int u = 0; u < 4; ++u) {
          int reg = tq * 4 + u;
          int grow = m0 + wr * 64 + mi * 32 + (u + 8 * tq + 4 * half);
          int s = grow & (S_ - 1), b = grow >> 11;
          float v = acc[mi][reg] + acc2[mi][reg] + bv;
          float other = __shfl_xor(v, 1);  // partner dim (d^1), lane^1
          float cs = cosT[(size_t)(b * S_ + s) * NT2 + tt];
          float sn = sinT[(size_t)(b * S_ + s) * NT2 + tt];
          float vr = (d & 1) ? (other * sn + v * cs) : (v * cs - other * sn);
          if (third == 0) vr *= 0.125f;  // 1/sqrt(D)
          bf16 hv = (bf16)vr;
          bf16 lv = (bf16)(vr - (float)hv);
          size_t idx = (((size_t)(b * H_ + h)) * S_ + s) * D_ + d;
          outH[idx] = hv;
          outL[idx] = lv;
        }
      }
    } else {  // V: bf16, transposed [B,H,D,S]
      const int h = gcol >> 6, d = gcol & 63;
#pragma unroll
      for (int tq = 0; tq < 4; ++tq) {
        int grow = m0 + wr * 64 + mi * 32 + (8 * tq + 4 * half);
        int s = grow & (S_ - 1), b = grow >> 11;
        ushort4 pk;
        unsigned short* pp = (unsigned short*)&pk;
#pragma unroll
        for (int u = 0; u < 4; ++u) {
          float v = acc[mi][tq * 4 + u] + acc2[mi][tq * 4 + u] + bv;
          bf16 hv = (bf16)v;
          pp[u] = __builtin_bit_cast(unsigned short, hv);
        }
        *(ushort4*)((unsigned short*)VTb +
                    (((size_t)(b * H_ + h)) * D_ + d) * S_ + s) = pk;
      }
    }
  }
}

// ---------------- O-projection split-bf16 GEMM: 64x128 tile, 2 blocks/CU ---
// Was 128^2/grid 256 = exactly 1 block/CU (the regime r10 proved bad).
// Now BM=64, BN=128, 256 thr / 4 waves (2M x 2N, wave tile 32x64), grid 512
// = 2 blocks/CU, LDS 24 KB.  Same merged layout + swizzle + acc-split.
#define BMo 64
#define BNo 128

__global__ __launch_bounds__(256, 4)
void gemm_o_kernel(const bf16* __restrict__ Ah_g, const bf16* __restrict__ Al_g,
                   const bf16* __restrict__ Bh_g, const bf16* __restrict__ Bl_g,
                   const float* __restrict__ bias, float* __restrict__ outF) {
  __shared__ bf16 lA[BMo * 64];  // 8 KB
  __shared__ bf16 lB[BNo * 64];  // 16 KB
  const int tid = threadIdx.x;
  const int n0 = blockIdx.x * BNo, m0 = blockIdx.y * BMo;
  const int wave = tid >> 6, lane = tid & 63;
  const int wr = wave >> 1, wc = wave & 1;  // 2M x 2N wave grid
  const int r = lane & 31, half = lane >> 5;
  const int KD = 1024;

  f32x16 acc[2] = {};   // ni = 0,1
  f32x16 acc2[2] = {};

  for (int kt = 0; kt < KD / BKg; ++kt) {
    const int k0 = kt * BKg;
    {
#pragma unroll
      for (int i = 0; i < 6; ++i) {  // 512 A-chunks + 1024 B-chunks
        int c = i * 256 + tid;
        if (i < 2) {  // A: chunks 0..511, rows 0..63
          int row = c >> 3, u = c & 7;
          int us = u ^ (row & 7);
          const bf16* sA = (us < 4) ? Ah_g : Al_g;
          char* lp = (char*)lA + (size_t)(i * 256 + wave * 64) * 16;
          gload_lds16((const char*)(sA + (size_t)(m0 + row) * KD + k0) +
                          (us & 3) * 16,
                      lp);
        } else {  // B: chunks 0..1023, rows 0..127
          int cb = c - 512;
          int row = cb >> 3, u = cb & 7;
          int us = u ^ (row & 7);
          const bf16* sB = (us < 4) ? Bh_g : Bl_g;
          char* lp = (char*)lB + (size_t)((i - 2) * 256 + wave * 64) * 16;
          gload_lds16((const char*)(sB + (size_t)(n0 + row) * KD + k0) +
                          (us & 3) * 16,
                      lp);
        }
      }
    }
    __syncthreads();
#pragma unroll
    for (int ks = 0; ks < 2; ++ks) {
      bf16x8 a_h, a_l, b_h[2], b_l[2];
      {
        int row = wr * 32 + r;
        int sw = (row & 7) << 4;
        const char* base = (const char*)lA + row * 128;
        a_h = *(const bf16x8*)(base + ((ks * 32 + half * 16) ^ sw));
        a_l = *(const bf16x8*)(base + ((64 + ks * 32 + half * 16) ^ sw));
      }
#pragma unroll
      for (int ni = 0; ni < 2; ++ni) {
        int row = wc * 64 + ni * 32 + r;
        int sw = (row & 7) << 4;
        const char* base = (const char*)lB + row * 128;
        b_h[ni] = *(const bf16x8*)(base + ((ks * 32 + half * 16) ^ sw));
        b_l[ni] = *(const bf16x8*)(base + ((64 + ks * 32 + half * 16) ^ sw));
      }
      __builtin_amdgcn_s_setprio(1);
#pragma unroll
      for (int ni = 0; ni < 2; ++ni) {
        acc[ni] = MFMA32(a_h, b_h[ni], acc[ni]);
        acc[ni] = MFMA32(a_h, b_l[ni], acc[ni]);
        acc2[ni] = MFMA32(a_l, b_h[ni], acc2[ni]);
      }
      __builtin_amdgcn_s_setprio(0);
    }
    __syncthreads();
  }

#pragma unroll
  for (int ni = 0; ni < 2; ++ni) {
    const int gcol = n0 + wc * 64 + ni * 32 + r;
    const float bv = bias[gcol];
#pragma unroll
    for (int tq = 0; tq < 4; ++tq)
#pragma unroll
      for (int u = 0; u < 4; ++u) {
        int grow = m0 + wr * 32 + (u + 8 * tq + 4 * half);
        outF[(size_t)grow * E_ + gcol] =
            acc[ni][tq * 4 + u] + acc2[ni][tq * 4 + u] + bv;
      }
  }
}

// ---------------- flash attention (in-register softmax, swapped QK^T) -------
__global__ __launch_bounds__(256)
void attn_kernel(const bf16* __restrict__ Qh, const bf16* __restrict__ Ql,
                 const bf16* __restrict__ Kh, const bf16* __restrict__ Kl,
                 const bf16* __restrict__ VT, bf16* __restrict__ Ch,
                 bf16* __restrict__ Cl) {
  __shared__ bf16 sKh[2][KVB * 64];
  __shared__ bf16 sKl[2][KVB * 64];
  __shared__ bf16 sV[2][KVB * 64];  // [d=64][key-pos=64], row-XOR-swizzled

  const int tid = threadIdx.x;
  const int wave = tid >> 6, lane = tid & 63;
  const int r = lane & 15, hq = lane >> 4;
  const int bid = blockIdx.x;
  const int swz = (bid & 7) * 64 + (bid >> 3);  // XCD-chunked (512 % 8 == 0)
  const int bh = swz >> 4, qblk = swz & 15;
  const int q0 = qblk * 128 + wave * 32;
  const size_t hb = (size_t)bh * (S_ * D_);
  const size_t vb = (size_t)bh * (D_ * S_);

  bf16x8 qh[2][2], ql[2][2];
#pragma unroll
  for (int mi = 0; mi < 2; ++mi)
#pragma unroll
    for (int ks = 0; ks < 2; ++ks) {
      size_t off = hb + (size_t)(q0 + mi * 16 + r) * D_ + ks * 32 + hq * 8;
      qh[mi][ks] = *(const bf16x8*)&Qh[off];
      ql[mi][ks] = *(const bf16x8*)&Ql[off];
    }

  float m_lane[2] = {-1e30f, -1e30f};
  float l_lane[2] = {0.f, 0.f};
  f32x4 o[2][4] = {};

  auto stageK = [&](int kt, int buf) {
    const bf16* kbh = Kh + hb + (size_t)kt * (KVB * D_);
    const bf16* kbl = Kl + hb + (size_t)kt * (KVB * D_);
#pragma unroll
    for (int i = 0; i < 2; ++i) {
      int c = i * 256 + tid;
      int ldo = (i * 256 + wave * 64) * 16;
      int cs = c ^ ((c >> 3) & 7);
      gload_lds16(kbh + cs * 8, (char*)&sKh[buf][0] + ldo);
      gload_lds16(kbl + cs * 8, (char*)&sKl[buf][0] + ldo);
    }
  };
  uint4 vld[2];
  auto loadV = [&](int kt) {
    const bf16* vbp = VT + vb + kt * KVB;
#pragma unroll
    for (int i = 0; i < 2; ++i) {
      int c = i * 256 + tid;
      int row = c >> 3, w = c & 7;
      vld[i] = *(const uint4*)(vbp + (size_t)row * S_ + w * 8);
    }
  };
  auto writeV = [&](int buf) {
#pragma unroll
    for (int i = 0; i < 2; ++i) {
      int c = i * 256 + tid;
      int row = c >> 3, w = c & 7;
      int pb0 = (w >> 2) * 32 + (w & 1) * 16 + ((w >> 1) & 1) * 4;
      char* base = (char*)&sV[buf][0] + row * 128;
      uint2 lo = {vld[i].x, vld[i].y};
      uint2 hi = {vld[i].z, vld[i].w};
      *(uint2*)(base + ((pb0 * 2) ^ ((row & 7) << 4))) = lo;
      *(uint2*)(base + (((pb0 + 8) * 2) ^ ((row & 7) << 4))) = hi;
    }
  };

  stageK(0, 0);
  loadV(0);
  writeV(0);
  __syncthreads();
  int cur = 0;

  for (int kt = 0; kt < S_ / KVB; ++kt) {
    if (kt + 1 < S_ / KVB) {
      stageK(kt + 1, cur ^ 1);
      loadV(kt + 1);
    }

    // ---- QK^T (swapped: A=K, B=Q) ----
    f32x4 sf[2][4] = {};
#pragma unroll
    for (int nf = 0; nf < 4; ++nf)
#pragma unroll
      for (int ks = 0; ks < 2; ++ks) {
        int kk = nf * 16 + r;
        int boff = (kk * 128 + ks * 64 + hq * 16) ^ ((kk & 7) << 4);
        bf16x8 kkh = *(const bf16x8*)((const char*)&sKh[cur][0] + boff);
        bf16x8 kkl = *(const bf16x8*)((const char*)&sKl[cur][0] + boff);
#pragma unroll
        for (int mi = 0; mi < 2; ++mi) {
          sf[mi][nf] = MFMA16(kkh, qh[mi][ks], sf[mi][nf]);
          sf[mi][nf] = MFMA16(kkh, ql[mi][ks], sf[mi][nf]);
          sf[mi][nf] = MFMA16(kkl, qh[mi][ks], sf[mi][nf]);
        }
      }

    // ---- defer-max online softmax (lane-local fast path) ----
    float lmax[2];
#pragma unroll
    for (int mi = 0; mi < 2; ++mi) {
      f32x4 m4;
#pragma unroll
      for (int e = 0; e < 4; ++e)
        m4[e] = fmaxf(fmaxf(sf[mi][0][e], sf[mi][1][e]),
                      fmaxf(sf[mi][2][e], sf[mi][3][e]));
      lmax[mi] = fmaxf(fmaxf(m4[0], m4[1]), fmaxf(m4[2], m4[3]));
    }
    int need = (lmax[0] > m_lane[0] + 8.f) || (lmax[1] > m_lane[1] + 8.f);
    if (__any(need)) {
#pragma unroll
      for (int mi = 0; mi < 2; ++mi) {
        float mx = lmax[mi];
        mx = fmaxf(mx, __shfl_xor(mx, 16));
        mx = fmaxf(mx, __shfl_xor(mx, 32));
        float mn = fmaxf(m_lane[mi], mx);
        float al = __expf(m_lane[mi] - mn);
        l_lane[mi] *= al;
        m_lane[mi] = mn;
        int alb = __builtin_bit_cast(int, al);
#pragma unroll
        for (int j = 0; j < 4; ++j) {
          int g = __builtin_amdgcn_ds_bpermute((hq * 4 + j) * 4, alb);
          float a = __builtin_bit_cast(float, g);
#pragma unroll
          for (int nd = 0; nd < 4; ++nd) o[mi][nd][j] *= a;
        }
      }
    }
    bf16x8 pa[2][2];
#pragma unroll
    for (int mi = 0; mi < 2; ++mi) {
      f32x4 s4 = {};
#pragma unroll
      for (int nf = 0; nf < 4; ++nf)
#pragma unroll
        for (int e = 0; e < 4; ++e) {
          float pv = __expf(sf[mi][nf][e] - m_lane[mi]);
          sf[mi][nf][e] = pv;
          s4[e] += pv;
        }
      l_lane[mi] += s4[0] + s4[1] + s4[2] + s4[3];
#pragma unroll
      for (int ks = 0; ks < 2; ++ks) {
        bf16x8 t;
#pragma unroll
        for (int e = 0; e < 4; ++e) {
          t[e] = (bf16)sf[mi][2 * ks][e];
          t[4 + e] = (bf16)sf[mi][2 * ks + 1][e];
        }
        pa[mi][ks] = t;
      }
    }

    // ---- PV ----
#pragma unroll
    for (int nd = 0; nd < 4; ++nd)
#pragma unroll
      for (int ks = 0; ks < 2; ++ks) {
        int dd = nd * 16 + r;
        int boff = (dd * 128 + ks * 64 + hq * 16) ^ ((dd & 7) << 4);
        bf16x8 vv = *(const bf16x8*)((const char*)&sV[cur][0] + boff);
#pragma unroll
        for (int mi = 0; mi < 2; ++mi)
          o[mi][nd] = MFMA16(pa[mi][ks], vv, o[mi][nd]);
      }

    if (kt + 1 < S_ / KVB) writeV(cur ^ 1);
    __syncthreads();
    cur ^= 1;
  }

  // ---- epilogue ----
  const int b = bh >> 4, h = bh & 15;
  float lq[2][4];
#pragma unroll
  for (int mi = 0; mi < 2; ++mi) {
    float lr = l_lane[mi];
    lr += __shfl_xor(lr, 16);
    lr += __shfl_xor(lr, 32);
    int lb = __builtin_bit_cast(int, lr);
#pragma unroll
    for (int j = 0; j < 4; ++j) {
      int g = __builtin_amdgcn_ds_bpermute((hq * 4 + j) * 4, lb);
      lq[mi][j] = __builtin_bit_cast(float, g);
    }
  }
#pragma unroll
  for (int mi = 0; mi < 2; ++mi)
#pragma unroll
    for (int nd = 0; nd < 4; ++nd)
#pragma unroll
      for (int j = 0; j < 4; ++j) {
        int s = q0 + mi * 16 + hq * 4 + j;
        int d = nd * 16 + r;
        float ov = o[mi][nd][j] / lq[mi][j];
        bf16 hv = (bf16)ov;
        bf16 lv = (bf16)(ov - (float)hv);
        size_t idx = (((size_t)(b * S_ + s)) * H_ + h) * D_ + d;
        Ch[idx] = hv;
        Cl[idx] = lv;
      }
}

// ---------------- host ----------------
extern "C" void kernel_launch(void* const* d_in, const int* in_sizes, int n_in,
                              void* d_out, int out_size, void* d_ws, size_t ws_size,
                              hipStream_t stream) {
  const float* x = (const float*)d_in[0];
  const int* pos = (const int*)d_in[1];
  const float* Wq = (const float*)d_in[2];
  const float* bq = (const float*)d_in[3];
  const float* Wk = (const float*)d_in[4];
  const float* bk = (const float*)d_in[5];
  const float* Wv = (const float*)d_in[6];
  const float* bv = (const float*)d_in[7];
  const float* Wo = (const float*)d_in[8];
  const float* bo = (const float*)d_in[9];
  float* out = (float*)d_out;

  char* p = (char*)d_ws;
  auto alloc = [&](size_t bytes) {
    char* rp = p;
    p += (bytes + 255) & ~(size_t)255;
    return rp;
  };
  const size_t XB = (size_t)M_ * E_ * sizeof(bf16);        // 8 MiB
  const size_t WB = (size_t)E_ * E_ * sizeof(bf16);        // 2 MiB
  const size_t TB = (size_t)B_ * S_ * NT2 * sizeof(float); // 256 KiB
  bf16* Xh = (bf16*)alloc(XB);
  bf16* Xl = (bf16*)alloc(XB);
  bf16* WqTh = (bf16*)alloc(WB); bf16* WqTl = (bf16*)alloc(WB);
  bf16* WkTh = (bf16*)alloc(WB); bf16* WkTl = (bf16*)alloc(WB);
  bf16* WvTh = (bf16*)alloc(WB); bf16* WvTl = (bf16*)alloc(WB);
  bf16* WoTh = (bf16*)alloc(WB); bf16* WoTl = (bf16*)alloc(WB);
  float* cosT = (float*)alloc(TB);
  float* sinT = (float*)alloc(TB);
  bf16* Qh = (bf16*)alloc(XB); bf16* Qlo = (bf16*)alloc(XB);
  bf16* Kh = (bf16*)alloc(XB); bf16* Klo = (bf16*)alloc(XB);
  bf16* VTb = (bf16*)alloc(XB);
  // ctx aliases X (X is dead after the QKV GEMM; attn runs after on same stream)
  bf16* Ch = Xh;
  bf16* Cl = Xl;

  prep_kernel<<<8704, 256, 0, stream>>>(x, pos, Wq, Wk, Wv, Wo, Xh, Xl, WqTh,
                                        WqTl, WkTh, WkTl, WvTh, WvTl, WoTh,
                                        WoTl, cosT, sinT);

  dim3 gq(24, 32);
  gemm_qkv_kernel<<<gq, 512, 0, stream>>>(Xh, Xl, WqTh, WqTl, WkTh, WkTl, WvTh,
                                          WvTl, bq, bk, bv, cosT, sinT, Qh, Qlo,
                                          Kh, Klo, VTb);

  attn_kernel<<<B_ * H_ * (S_ / 128), 256, 0, stream>>>(Qh, Qlo, Kh, Klo, VTb,
                                                        Ch, Cl);

  dim3 go(8, 64);
  gemm_o_kernel<<<go, 256, 0, stream>>>(Ch, Cl, WoTh, WoTl, bo, out);
}